// Round 7
// baseline (3013.455 us; speedup 1.0000x reference)
//
#include <hip/hip_runtime.h>
#include <hip/hip_fp16.h>

#define NN 200000
#define EE 6400000
#define GG 1024
#define HH 256
#define RR 8          // deg_out replicas
#define NB 782        // buckets = ceil(NN/256)
#define NC 782        // edge chunks = ceil(EE/8192)
#define CHUNK 8192
#define CAP 9216      // LDS stage capacity per bucket (mean 8184, sigma ~90)

typedef _Float16 half8 __attribute__((ext_vector_type(8)));
typedef float floatx4 __attribute__((ext_vector_type(4)));

__device__ __forceinline__ float fast_tanh(float x) {
  float e = __expf(2.0f * x);
  return 1.0f - 2.0f / (e + 1.0f);
}

// deg_out histogram with replicated counters
__global__ void degree_src_kernel(const int* __restrict__ src, int* __restrict__ doutR) {
  int e = blockIdx.x * blockDim.x + threadIdx.x;
  if (e >= EE) return;
  atomicAdd(&doutR[(e & (RR - 1)) * NN + src[e]], 1);
}

// g_ptr from sorted gid boundaries
__global__ void gptr_kernel(const int* __restrict__ gid, int* __restrict__ g_ptr) {
  int n = blockIdx.x * blockDim.x + threadIdx.x;
  if (n >= NN) return;
  int g = gid[n];
  int gp = (n == 0) ? -1 : gid[n - 1];
  for (int x = gp + 1; x <= g; ++x) g_ptr[x] = n;
  if (n == NN - 1) {
    for (int x = g + 1; x <= GG; ++x) g_ptr[x] = NN;
  }
}

// pass-1 histogram: per-chunk bucket counts, bucket-major output
__global__ __launch_bounds__(256) void hist1_kernel(const int* __restrict__ dst,
                                                    int* __restrict__ hist_t) {
  __shared__ int h[NB];
  int c = blockIdx.x, t = threadIdx.x;
  for (int b = t; b < NB; b += 256) h[b] = 0;
  __syncthreads();
  int e0 = c * CHUNK, e1 = min(e0 + CHUNK, EE);
  for (int e = e0 + t; e < e1; e += 256) atomicAdd(&h[dst[e] >> 8], 1);
  __syncthreads();
  for (int b = t; b < NB; b += 256) hist_t[b * NC + c] = h[b];
}

// scan stage A: 1024 elems/block (4/thread), in-place exclusive, emits block sums
__global__ __launch_bounds__(256) void scanA4_kernel(int* __restrict__ a, int n,
                                                     int* __restrict__ bsum) {
  __shared__ int ws4[4];
  int t = threadIdx.x;
  int base = blockIdx.x * 1024 + t * 4;
  int v0 = 0, v1 = 0, v2 = 0, v3 = 0;
  if (base + 3 < n) {
    int4 q = *(const int4*)(a + base);
    v0 = q.x; v1 = q.y; v2 = q.z; v3 = q.w;
  } else {
    if (base + 0 < n) v0 = a[base + 0];
    if (base + 1 < n) v1 = a[base + 1];
    if (base + 2 < n) v2 = a[base + 2];
    if (base + 3 < n) v3 = a[base + 3];
  }
  int s = v0 + v1 + v2 + v3;
  int lane = t & 63, w = t >> 6;
  int x = s;
  for (int off = 1; off < 64; off <<= 1) {
    int y = __shfl_up(x, off);
    if (lane >= off) x += y;
  }
  if (lane == 63) ws4[w] = x;
  __syncthreads();
  if (t == 0) {
    int acc = 0;
    for (int k = 0; k < 4; ++k) { int tmp = ws4[k]; ws4[k] = acc; acc += tmp; }
  }
  __syncthreads();
  int e = ws4[w] + x - s;
  int o0 = e, o1 = e + v0, o2 = o1 + v1, o3 = o2 + v2;
  if (base + 3 < n) {
    int4 q; q.x = o0; q.y = o1; q.z = o2; q.w = o3;
    *(int4*)(a + base) = q;
  } else {
    if (base + 0 < n) a[base + 0] = o0;
    if (base + 1 < n) a[base + 1] = o1;
    if (base + 2 < n) a[base + 2] = o2;
    if (base + 3 < n) a[base + 3] = o3;
  }
  if (t == 255) bsum[blockIdx.x] = ws4[3] + x;
}

// stage B: single-block exclusive scan of block sums (nb <= 1024)
__global__ __launch_bounds__(1024) void scanB_kernel(const int* __restrict__ bsum, int nb,
                                                     int* __restrict__ boffs) {
  __shared__ int wsum[16];
  int t = threadIdx.x;
  int lane = t & 63, w = t >> 6;
  int v = (t < nb) ? bsum[t] : 0;
  int x = v;
  for (int off = 1; off < 64; off <<= 1) {
    int y = __shfl_up(x, off);
    if (lane >= off) x += y;
  }
  if (lane == 63) wsum[w] = x;
  __syncthreads();
  if (t < 16) {
    int s = wsum[t];
    for (int off = 1; off < 16; off <<= 1) {
      int y = __shfl_up(s, off);
      if (t >= off) s += y;
    }
    wsum[t] = s;
  }
  __syncthreads();
  int waveoff = (w > 0) ? wsum[w - 1] : 0;
  int excl = waveoff + (x - v);
  if (t <= nb) boffs[t] = excl;
}

__global__ void addC4_kernel(int* __restrict__ a, int n, const int* __restrict__ boffs) {
  int i = blockIdx.x * blockDim.x + threadIdx.x;
  if (i < n) a[i] += boffs[i >> 10];
}

__global__ void bucketptr_kernel(const int* __restrict__ hist_t, int* __restrict__ bucket_ptr) {
  int b = blockIdx.x * blockDim.x + threadIdx.x;
  if (b < NB) bucket_ptr[b] = hist_t[b * NC];
  if (b == NB) bucket_ptr[NB] = EE;
}

// pass-1 scatter: edges -> (dst,src) pairs grouped by bucket
__global__ __launch_bounds__(256) void scatter1_kernel(const int* __restrict__ src,
                                                       const int* __restrict__ dst,
                                                       const int* __restrict__ hist_t,
                                                       uint2* __restrict__ pairs) {
  __shared__ int cur[NB];
  int c = blockIdx.x, t = threadIdx.x;
  for (int b = t; b < NB; b += 256) cur[b] = hist_t[b * NC + c];
  __syncthreads();
  int e0 = c * CHUNK, e1 = min(e0 + CHUNK, EE);
  for (int e = e0 + t; e < e1; e += 256) {
    int d = dst[e], s = src[e];
    int pos = atomicAdd(&cur[d >> 8], 1);
    uint2 p; p.x = (unsigned)d; p.y = (unsigned)s;
    pairs[pos] = p;
  }
}

// pass-2: per-bucket counting sort in LDS; emits col (coalesced) + row_ptr
__global__ __launch_bounds__(256) void bucket_kernel(const uint2* __restrict__ pairs,
                                                     const int* __restrict__ bucket_ptr,
                                                     int* __restrict__ col,
                                                     int* __restrict__ row_ptr) {
  __shared__ int rhist[256];
  __shared__ int rcur[256];
  __shared__ int ws4[4];
  __shared__ int stage[CAP];
  int b = blockIdx.x, t = threadIdx.x;
  int row0 = b << 8;
  int p0 = bucket_ptr[b], p1 = bucket_ptr[b + 1];
  int cnt = p1 - p0;
  rhist[t] = 0;
  __syncthreads();
  for (int i = t; i < cnt; i += 256) {
    int d = (int)pairs[p0 + i].x;
    atomicAdd(&rhist[d & 255], 1);
  }
  __syncthreads();
  int v = rhist[t];
  int lane = t & 63, w = t >> 6;
  int x = v;
  for (int off = 1; off < 64; off <<= 1) {
    int y = __shfl_up(x, off);
    if (lane >= off) x += y;
  }
  if (lane == 63) ws4[w] = x;
  __syncthreads();
  if (t == 0) {
    int acc = 0;
    for (int k = 0; k < 4; ++k) { int tmp = ws4[k]; ws4[k] = acc; acc += tmp; }
  }
  __syncthreads();
  int excl = ws4[w] + x - v;
  rcur[t] = excl;
  int row = row0 + t;
  if (row < NN) row_ptr[row] = p0 + excl;
  if (b == NB - 1 && t == 0) row_ptr[NN] = EE;
  __syncthreads();
  for (int i = t; i < cnt; i += 256) {
    uint2 p = pairs[p0 + i];
    int pos = atomicAdd(&rcur[(int)p.x & 255], 1);
    if (pos < CAP) stage[pos] = (int)p.y;
    else col[p0 + pos] = (int)p.y;  // overflow guard (statistically never)
  }
  __syncthreads();
  int lim = min(cnt, CAP);
  for (int i = t; i < lim; i += 256) col[p0 + i] = stage[i];
}

__global__ void feature_kernel(const int* __restrict__ row_ptr, const int* __restrict__ doutR,
                               float* __restrict__ norm_src, float* __restrict__ norm_dst,
                               float4* __restrict__ xs1) {
  int n = blockIdx.x * blockDim.x + threadIdx.x;
  if (n >= NN) return;
  int dii = row_ptr[n + 1] - row_ptr[n];
  int doo = 0;
#pragma unroll
  for (int r = 0; r < RR; ++r) doo += doutR[r * NN + n];
  float di = (float)dii;
  float dofl = (float)doo;
  float ns = rsqrtf(fmaxf(dofl, 1.0f));
  float nd = rsqrtf(fmaxf(di, 1.0f));
  norm_src[n] = ns;
  norm_dst[n] = nd;
  float h1 = di;
  float h2 = (di - 3.0f > 0.0f) ? 1.0f : 0.0f;
  float h3 = 3.0f / di;
  float h4 = (di - 4.0f > 0.0f) ? 1.0f : 0.0f;
  float4 o;
  o.x = h1 * ns; o.y = h2 * ns; o.z = h3 * ns; o.w = h4 * ns;
  xs1[n] = o;
}

__global__ void spmm4_kernel(const int* __restrict__ rp, const int* __restrict__ col,
                             const float4* __restrict__ xs1, const float* __restrict__ norm_dst,
                             float4* __restrict__ agg4) {
  int n = blockIdx.x * blockDim.x + threadIdx.x;
  if (n >= NN) return;
  int e0 = rp[n], e1 = rp[n + 1];
  float ax = 0.f, ay = 0.f, az = 0.f, aw = 0.f;
  for (int e = e0; e < e1; ++e) {
    int s = __builtin_nontemporal_load(&col[e]);
    float4 v = xs1[s];
    ax += v.x; ay += v.y; az += v.z; aw += v.w;
  }
  float nd = norm_dst[n];
  float4 o; o.x = ax * nd; o.y = ay * nd; o.z = az * nd; o.w = aw * nd;
  agg4[n] = o;
}

__device__ __forceinline__ void acc_half2(unsigned v, float& a0, float& a1) {
  __half2 h = *reinterpret_cast<__half2*>(&v);
  float2 f = __half22float2(h);
  a0 += f.x; a1 += f.y;
}

// one wave per dst row, HALF feature range (128 cols); lane holds 2 f16; 16x unrolled
__global__ __launch_bounds__(256) void spmm128_kernel(
    const int* __restrict__ rp, const int* __restrict__ col,
    const __half* __restrict__ hs, const float* __restrict__ norm_dst,
    __half* __restrict__ aggH, int half) {
  int wid = (blockIdx.x * blockDim.x + threadIdx.x) >> 6;
  int lane = threadIdx.x & 63;
  if (wid >= NN) return;
  int e0 = rp[wid], e1 = rp[wid + 1];
  float a0 = 0.f, a1 = 0.f;
  const __half* hp = hs + half * 128 + lane * 2;
  int e = e0;
  for (; e + 16 <= e1; e += 16) {
    int s[16];
#pragma unroll
    for (int u = 0; u < 16; ++u)
      s[u] = __builtin_amdgcn_readfirstlane(__builtin_nontemporal_load(&col[e + u]));
    unsigned v[16];
#pragma unroll
    for (int u = 0; u < 16; ++u) v[u] = *(const unsigned*)(hp + (size_t)s[u] * HH);
#pragma unroll
    for (int u = 0; u < 16; ++u) acc_half2(v[u], a0, a1);
  }
  for (; e + 4 <= e1; e += 4) {
    int s[4];
#pragma unroll
    for (int u = 0; u < 4; ++u)
      s[u] = __builtin_amdgcn_readfirstlane(__builtin_nontemporal_load(&col[e + u]));
    unsigned v[4];
#pragma unroll
    for (int u = 0; u < 4; ++u) v[u] = *(const unsigned*)(hp + (size_t)s[u] * HH);
#pragma unroll
    for (int u = 0; u < 4; ++u) acc_half2(v[u], a0, a1);
  }
  for (; e < e1; ++e) {
    int s = __builtin_amdgcn_readfirstlane(__builtin_nontemporal_load(&col[e]));
    unsigned v = *(const unsigned*)(hp + (size_t)s * HH);
    acc_half2(v, a0, a1);
  }
  float nd = norm_dst[wid];
  __half2 p = __floats2half2_rn(a0 * nd, a1 * nd);
  __builtin_nontemporal_store(*(unsigned*)&p,
                              (unsigned*)(aggH + (size_t)wid * HH + half * 128 + lane * 2));
}

// layer-1 transform (K=4), VALU path
__global__ __launch_bounds__(256) void transform4_kernel(
    const float* __restrict__ agg, const float* __restrict__ W, const float* __restrict__ b,
    const float* __restrict__ norm_src, __half* __restrict__ hs_out) {
  __shared__ float tile[64 * 4];
  int t = threadIdx.x;
  int rowbase = blockIdx.x * 64;
  const float4* srcp = (const float4*)(agg + (size_t)rowbase * 4);
  float4* dst4 = (float4*)tile;
  for (int i = t; i < 64; i += 256) dst4[i] = srcp[i];
  __syncthreads();
  int w = t >> 6, lane = t & 63;
  int c0 = lane * 4;
  float acc[16][4];
#pragma unroll
  for (int r = 0; r < 16; ++r) {
    acc[r][0] = 0.f; acc[r][1] = 0.f; acc[r][2] = 0.f; acc[r][3] = 0.f;
  }
  const float* tw = tile + (size_t)(w * 16) * 4;
#pragma unroll
  for (int k = 0; k < 4; ++k) {
    float4 wv = *(const float4*)(W + (size_t)k * HH + c0);
#pragma unroll
    for (int r = 0; r < 16; ++r) {
      float a = tw[r * 4 + k];
      acc[r][0] += a * wv.x;
      acc[r][1] += a * wv.y;
      acc[r][2] += a * wv.z;
      acc[r][3] += a * wv.w;
    }
  }
  float4 bv = *(const float4*)(b + c0);
#pragma unroll
  for (int r = 0; r < 16; ++r) {
    int row = rowbase + w * 16 + r;
    float ns = norm_src[row];
    float y0 = fast_tanh(acc[r][0] + bv.x) * ns;
    float y1 = fast_tanh(acc[r][1] + bv.y) * ns;
    float y2 = fast_tanh(acc[r][2] + bv.z) * ns;
    float y3 = fast_tanh(acc[r][3] + bv.w) * ns;
    __half2 p0 = __floats2half2_rn(y0, y1);
    __half2 p1 = __floats2half2_rn(y2, y3);
    uint2 o = make_uint2(*(unsigned*)&p0, *(unsigned*)&p1);
    *(uint2*)(hs_out + (size_t)row * HH + c0) = o;
  }
}

// repack all 4 W [256,256] fp32 row-major into fragment-contiguous f16
__global__ void repack_w_kernel(const float* __restrict__ W2, const float* __restrict__ W3,
                                const float* __restrict__ W4, const float* __restrict__ W5,
                                __half* __restrict__ Wf) {
  int t = blockIdx.x * blockDim.x + threadIdx.x;  // 4*65536 threads
  int which = t >> 16;
  int u = t & 65535;
  const float* W = (which == 0) ? W2 : (which == 1) ? W3 : (which == 2) ? W4 : W5;
  int b = u & 7;
  int lane = (u >> 3) & 63;
  int tile = (u >> 9) & 15;
  int ks = u >> 13;
  int k = ks * 32 + (lane >> 4) * 8 + b;
  int c = tile * 16 + (lane & 15);
  Wf[t] = __float2half(W[k * HH + c]);
}

// MFMA transform: out = tanh(aggH @ W + b); A operand f16 direct
__global__ __launch_bounds__(256) void gemm_mfma_kernel(
    const __half* __restrict__ aggH, const __half* __restrict__ Wf,
    const float* __restrict__ bias, const float* __restrict__ norm_src,
    __half* __restrict__ hs_out, float* h_out) {
  int w = threadIdx.x >> 6;
  int lane = threadIdx.x & 63;
  int l15 = lane & 15, l4 = lane >> 4;
  int row0 = blockIdx.x * 64;
  floatx4 acc[4][4];
#pragma unroll
  for (int m = 0; m < 4; ++m)
#pragma unroll
    for (int n = 0; n < 4; ++n) acc[m][n] = (floatx4)(0.0f);

#pragma unroll
  for (int ks = 0; ks < 8; ++ks) {
    int k0 = ks * 32 + l4 * 8;
    half8 af[4];
#pragma unroll
    for (int m = 0; m < 4; ++m)
      af[m] = *(const half8*)(aggH + (size_t)(row0 + m * 16 + l15) * HH + k0);
    half8 bf[4];
#pragma unroll
    for (int n = 0; n < 4; ++n)
      bf[n] = *(const half8*)(Wf + ((size_t)(ks * 16 + w * 4 + n) * 64 + lane) * 8);
#pragma unroll
    for (int m = 0; m < 4; ++m)
#pragma unroll
      for (int n = 0; n < 4; ++n)
        acc[m][n] = __builtin_amdgcn_mfma_f32_16x16x32_f16(af[m], bf[n], acc[m][n], 0, 0, 0);
  }

  float ns[16];
  if (!h_out) {
#pragma unroll
    for (int m = 0; m < 4; ++m)
#pragma unroll
      for (int r = 0; r < 4; ++r) ns[m * 4 + r] = norm_src[row0 + m * 16 + l4 * 4 + r];
  }
#pragma unroll
  for (int n = 0; n < 4; ++n) {
    int c = w * 64 + n * 16 + l15;
    float bb = bias[c];
#pragma unroll
    for (int m = 0; m < 4; ++m) {
#pragma unroll
      for (int r = 0; r < 4; ++r) {
        int row = row0 + m * 16 + l4 * 4 + r;
        float y = fast_tanh(acc[m][n][r] + bb);
        if (h_out) {
          h_out[(size_t)row * HH + c] = y;
        } else {
          hs_out[(size_t)row * HH + c] = (__half)(y * ns[m * 4 + r]);
        }
      }
    }
  }
}

__global__ void mean_kernel(const float* __restrict__ h, const int* __restrict__ g_ptr,
                            float* __restrict__ emb) {
  int g = blockIdx.x;
  int j = threadIdx.x;  // 256 threads
  int s = g_ptr[g], e = g_ptr[g + 1];
  float sum = 0.f;
  for (int n = s; n < e; ++n) sum += h[(size_t)n * HH + j];
  int cnt = e - s;
  emb[(size_t)g * HH + j] = (cnt > 0) ? sum / (float)cnt : 0.0f;
}

__global__ __launch_bounds__(128) void mlp_kernel(const float* __restrict__ emb,
                                                  const float* __restrict__ Wl1,
                                                  const float* __restrict__ bl1,
                                                  const float* __restrict__ Wl2,
                                                  const float* __restrict__ bl2,
                                                  float* __restrict__ pred) {
  __shared__ float se[256];
  __shared__ float sh[128];
  int g = blockIdx.x, t = threadIdx.x;
  se[t] = emb[(size_t)g * HH + t];
  se[t + 128] = emb[(size_t)g * HH + t + 128];
  __syncthreads();
  float acc = bl1[t];
  for (int k = 0; k < 256; ++k) acc += se[k] * Wl1[k * 128 + t];
  float he = (acc > 0.f) ? acc : 0.01f * acc;
  sh[t] = he * Wl2[t];
  __syncthreads();
  if (t < 64) sh[t] += sh[t + 64];
  __syncthreads();
  if (t < 64) {
    float v = sh[t];
    for (int off = 32; off > 0; off >>= 1) v += __shfl_down(v, off);
    if (t == 0) {
      float z = v + bl2[0];
      pred[g] = 1.0f / (1.0f + expf(-z));
    }
  }
}

extern "C" void kernel_launch(void* const* d_in, const int* in_sizes, int n_in,
                              void* d_out, int out_size, void* d_ws, size_t ws_size,
                              hipStream_t stream) {
  const int* src = (const int*)d_in[0];
  const int* dst = (const int*)d_in[1];
  const int* gid = (const int*)d_in[2];
  const float* W1 = (const float*)d_in[3];
  const float* b1 = (const float*)d_in[4];
  const float* W2 = (const float*)d_in[5];
  const float* b2 = (const float*)d_in[6];
  const float* W3 = (const float*)d_in[7];
  const float* b3 = (const float*)d_in[8];
  const float* W4 = (const float*)d_in[9];
  const float* b4 = (const float*)d_in[10];
  const float* W5 = (const float*)d_in[11];
  const float* b5 = (const float*)d_in[12];
  const float* Wl1 = (const float*)d_in[13];
  const float* bl1 = (const float*)d_in[14];
  const float* Wl2 = (const float*)d_in[15];
  const float* bl2 = (const float*)d_in[16];

  char* ws = (char*)d_ws;
  size_t off = 0;
  auto alloc = [&](size_t bytes) -> void* {
    void* p = ws + off;
    off += (bytes + 255) & ~(size_t)255;
    return p;
  };

  int* col = (int*)alloc((size_t)EE * 4);
  int* row_ptr = (int*)alloc((size_t)(NN + 1) * 4);
  int* hist_t = (int*)alloc((size_t)NB * NC * 4);
  int* bucket_ptr = (int*)alloc((size_t)(NB + 1) * 4);
  int* bsum = (int*)alloc(1024 * 4);
  int* boffs = (int*)alloc(1025 * 4);
  int* g_ptr = (int*)alloc((size_t)(GG + 1) * 4);
  float* norm_src = (float*)alloc((size_t)NN * 4);
  float* norm_dst = (float*)alloc((size_t)NN * 4);
  float4* xs1 = (float4*)alloc((size_t)NN * 16);
  float4* agg4 = (float4*)alloc((size_t)NN * 16);
  __half* Wf = (__half*)alloc((size_t)4 * HH * HH * 2);
  int* doutR = (int*)alloc((size_t)RR * NN * 4);
  // union: pairs (51.2 MB) dies before aggH (102.4 MB) is born
  void* unionp = alloc((size_t)NN * HH * 2);
  uint2* pairs = (uint2*)unionp;
  __half* aggH = (__half*)unionp;

  float* outp = (float*)d_out;
  float* pred = outp;
  float* emb = outp + GG;
  float* hreg = outp + GG + (size_t)GG * HH;  // final h fp32 (written fully at layer 5)
  // hs (f16, 102.4 MB) lives in the h region; dead before layer-5 gemm writes h
  __half* hs = (__half*)hreg;

  hipMemsetAsync(doutR, 0, (size_t)RR * NN * 4, stream);

  degree_src_kernel<<<(EE + 255) / 256, 256, 0, stream>>>(src, doutR);
  gptr_kernel<<<(NN + 255) / 256, 256, 0, stream>>>(gid, g_ptr);
  repack_w_kernel<<<1024, 256, 0, stream>>>(W2, W3, W4, W5, Wf);

  const int nscan = NB * NC;                  // 611,524
  const int nbA = (nscan + 1023) / 1024;      // 598
  hist1_kernel<<<NC, 256, 0, stream>>>(dst, hist_t);
  scanA4_kernel<<<nbA, 256, 0, stream>>>(hist_t, nscan, bsum);
  scanB_kernel<<<1, 1024, 0, stream>>>(bsum, nbA, boffs);
  addC4_kernel<<<(nscan + 255) / 256, 256, 0, stream>>>(hist_t, nscan, boffs);
  bucketptr_kernel<<<(NB + 256) / 256, 256, 0, stream>>>(hist_t, bucket_ptr);
  scatter1_kernel<<<NC, 256, 0, stream>>>(src, dst, hist_t, pairs);
  bucket_kernel<<<NB, 256, 0, stream>>>(pairs, bucket_ptr, col, row_ptr);

  feature_kernel<<<(NN + 255) / 256, 256, 0, stream>>>(row_ptr, doutR, norm_src, norm_dst, xs1);

  spmm4_kernel<<<(NN + 255) / 256, 256, 0, stream>>>(row_ptr, col, xs1, norm_dst, agg4);
  transform4_kernel<<<NN / 64, 256, 0, stream>>>((const float*)agg4, W1, b1, norm_src, hs);

  const float* bs[4] = {b2, b3, b4, b5};
  for (int l = 0; l < 4; ++l) {
    spmm128_kernel<<<NN / 4, 256, 0, stream>>>(row_ptr, col, hs, norm_dst, aggH, 0);
    spmm128_kernel<<<NN / 4, 256, 0, stream>>>(row_ptr, col, hs, norm_dst, aggH, 1);
    gemm_mfma_kernel<<<NN / 64, 256, 0, stream>>>(
        aggH, Wf + (size_t)l * HH * HH, bs[l], norm_src,
        hs, (l == 3) ? hreg : (float*)nullptr);
  }

  mean_kernel<<<GG, 256, 0, stream>>>(hreg, g_ptr, emb);
  mlp_kernel<<<GG, 128, 0, stream>>>(emb, Wl1, bl1, Wl2, bl2, pred);
}

// Round 8
// 2968.578 us; speedup vs baseline: 1.0151x; 1.0151x over previous
//
#include <hip/hip_runtime.h>
#include <hip/hip_fp16.h>

#define NN 200000
#define EE 6400000
#define GG 1024
#define HH 256
#define NB 782        // buckets = ceil(NN/256)
#define NC 782        // edge chunks = ceil(EE/8192)
#define CHUNK 8192
#define CAP 9216      // LDS stage capacity per bucket
#define LP 264        // LDS row pitch in halves (256 + 8 pad)

typedef _Float16 half8 __attribute__((ext_vector_type(8)));
typedef float floatx4 __attribute__((ext_vector_type(4)));
typedef unsigned int uintx2 __attribute__((ext_vector_type(2)));

__device__ __forceinline__ float fast_tanh(float x) {
  float e = __expf(2.0f * x);
  return 1.0f - 2.0f / (e + 1.0f);
}

// g_ptr from sorted gid boundaries
__global__ void gptr_kernel(const int* __restrict__ gid, int* __restrict__ g_ptr) {
  int n = blockIdx.x * blockDim.x + threadIdx.x;
  if (n >= NN) return;
  int g = gid[n];
  int gp = (n == 0) ? -1 : gid[n - 1];
  for (int x = gp + 1; x <= g; ++x) g_ptr[x] = n;
  if (n == NN - 1) {
    for (int x = g + 1; x <= GG; ++x) g_ptr[x] = NN;
  }
}

// per-chunk bucket counts of key[], bucket-major output
__global__ __launch_bounds__(256) void hist1_kernel(const int* __restrict__ key,
                                                    int* __restrict__ hist_t) {
  __shared__ int h[NB];
  int c = blockIdx.x, t = threadIdx.x;
  for (int b = t; b < NB; b += 256) h[b] = 0;
  __syncthreads();
  int e0 = c * CHUNK, e1 = min(e0 + CHUNK, EE);
  for (int e = e0 + t; e < e1; e += 256) atomicAdd(&h[key[e] >> 8], 1);
  __syncthreads();
  for (int b = t; b < NB; b += 256) hist_t[b * NC + c] = h[b];
}

// scan stage A: 1024 elems/block (4/thread), in-place exclusive, emits block sums
__global__ __launch_bounds__(256) void scanA4_kernel(int* __restrict__ a, int n,
                                                     int* __restrict__ bsum) {
  __shared__ int ws4[4];
  int t = threadIdx.x;
  int base = blockIdx.x * 1024 + t * 4;
  int v0 = 0, v1 = 0, v2 = 0, v3 = 0;
  if (base + 3 < n) {
    int4 q = *(const int4*)(a + base);
    v0 = q.x; v1 = q.y; v2 = q.z; v3 = q.w;
  } else {
    if (base + 0 < n) v0 = a[base + 0];
    if (base + 1 < n) v1 = a[base + 1];
    if (base + 2 < n) v2 = a[base + 2];
    if (base + 3 < n) v3 = a[base + 3];
  }
  int s = v0 + v1 + v2 + v3;
  int lane = t & 63, w = t >> 6;
  int x = s;
  for (int off = 1; off < 64; off <<= 1) {
    int y = __shfl_up(x, off);
    if (lane >= off) x += y;
  }
  if (lane == 63) ws4[w] = x;
  __syncthreads();
  if (t == 0) {
    int acc = 0;
    for (int k = 0; k < 4; ++k) { int tmp = ws4[k]; ws4[k] = acc; acc += tmp; }
  }
  __syncthreads();
  int e = ws4[w] + x - s;
  int o0 = e, o1 = e + v0, o2 = o1 + v1, o3 = o2 + v2;
  if (base + 3 < n) {
    int4 q; q.x = o0; q.y = o1; q.z = o2; q.w = o3;
    *(int4*)(a + base) = q;
  } else {
    if (base + 0 < n) a[base + 0] = o0;
    if (base + 1 < n) a[base + 1] = o1;
    if (base + 2 < n) a[base + 2] = o2;
    if (base + 3 < n) a[base + 3] = o3;
  }
  if (t == 255) bsum[blockIdx.x] = ws4[3] + x;
}

// stage B: single-block exclusive scan of block sums (nb <= 1024)
__global__ __launch_bounds__(1024) void scanB_kernel(const int* __restrict__ bsum, int nb,
                                                     int* __restrict__ boffs) {
  __shared__ int wsum[16];
  int t = threadIdx.x;
  int lane = t & 63, w = t >> 6;
  int v = (t < nb) ? bsum[t] : 0;
  int x = v;
  for (int off = 1; off < 64; off <<= 1) {
    int y = __shfl_up(x, off);
    if (lane >= off) x += y;
  }
  if (lane == 63) wsum[w] = x;
  __syncthreads();
  if (t < 16) {
    int s = wsum[t];
    for (int off = 1; off < 16; off <<= 1) {
      int y = __shfl_up(s, off);
      if (t >= off) s += y;
    }
    wsum[t] = s;
  }
  __syncthreads();
  int waveoff = (w > 0) ? wsum[w - 1] : 0;
  int excl = waveoff + (x - v);
  if (t <= nb) boffs[t] = excl;
}

__global__ void addC4_kernel(int* __restrict__ a, int n, const int* __restrict__ boffs) {
  int i = blockIdx.x * blockDim.x + threadIdx.x;
  if (i < n) a[i] += boffs[i >> 10];
}

__global__ void bucketptr_kernel(const int* __restrict__ hist_t, int* __restrict__ bucket_ptr) {
  int b = blockIdx.x * blockDim.x + threadIdx.x;
  if (b < NB) bucket_ptr[b] = hist_t[b * NC];
  if (b == NB) bucket_ptr[NB] = EE;
}

// pass-1 scatter: edges -> (dst,src) pairs grouped by dst-bucket
__global__ __launch_bounds__(256) void scatter1_kernel(const int* __restrict__ src,
                                                       const int* __restrict__ dst,
                                                       const int* __restrict__ hist_t,
                                                       uint2* __restrict__ pairs) {
  __shared__ int cur[NB];
  int c = blockIdx.x, t = threadIdx.x;
  for (int b = t; b < NB; b += 256) cur[b] = hist_t[b * NC + c];
  __syncthreads();
  int e0 = c * CHUNK, e1 = min(e0 + CHUNK, EE);
  for (int e = e0 + t; e < e1; e += 256) {
    int d = dst[e], s = src[e];
    int pos = atomicAdd(&cur[d >> 8], 1);
    uint2 p; p.x = (unsigned)d; p.y = (unsigned)s;
    pairs[pos] = p;
  }
}

// pass-2: per-bucket counting sort in LDS; emits col (coalesced) + row_ptr
__global__ __launch_bounds__(256) void bucket_kernel(const uint2* __restrict__ pairs,
                                                     const int* __restrict__ bucket_ptr,
                                                     int* __restrict__ col,
                                                     int* __restrict__ row_ptr) {
  __shared__ int rhist[256];
  __shared__ int rcur[256];
  __shared__ int ws4[4];
  __shared__ int stage[CAP];
  int b = blockIdx.x, t = threadIdx.x;
  int row0 = b << 8;
  int p0 = bucket_ptr[b], p1 = bucket_ptr[b + 1];
  int cnt = p1 - p0;
  rhist[t] = 0;
  __syncthreads();
  for (int i = t; i < cnt; i += 256) {
    int d = (int)pairs[p0 + i].x;
    atomicAdd(&rhist[d & 255], 1);
  }
  __syncthreads();
  int v = rhist[t];
  int lane = t & 63, w = t >> 6;
  int x = v;
  for (int off = 1; off < 64; off <<= 1) {
    int y = __shfl_up(x, off);
    if (lane >= off) x += y;
  }
  if (lane == 63) ws4[w] = x;
  __syncthreads();
  if (t == 0) {
    int acc = 0;
    for (int k = 0; k < 4; ++k) { int tmp = ws4[k]; ws4[k] = acc; acc += tmp; }
  }
  __syncthreads();
  int excl = ws4[w] + x - v;
  rcur[t] = excl;
  int row = row0 + t;
  if (row < NN) row_ptr[row] = p0 + excl;
  if (b == NB - 1 && t == 0) row_ptr[NN] = EE;
  __syncthreads();
  for (int i = t; i < cnt; i += 256) {
    uint2 p = pairs[p0 + i];
    int pos = atomicAdd(&rcur[(int)p.x & 255], 1);
    if (pos < CAP) stage[pos] = (int)p.y;
    else col[p0 + pos] = (int)p.y;  // overflow guard (statistically never)
  }
  __syncthreads();
  int lim = min(cnt, CAP);
  for (int i = t; i < lim; i += 256) col[p0 + i] = stage[i];
}

// scatter src values grouped by src-bucket (payload = value itself)
__global__ __launch_bounds__(256) void scatter_src_kernel(const int* __restrict__ src,
                                                          const int* __restrict__ hist_t,
                                                          int* __restrict__ out) {
  __shared__ int cur[NB];
  int c = blockIdx.x, t = threadIdx.x;
  for (int b = t; b < NB; b += 256) cur[b] = hist_t[b * NC + c];
  __syncthreads();
  int e0 = c * CHUNK, e1 = min(e0 + CHUNK, EE);
  for (int e = e0 + t; e < e1; e += 256) {
    int v = src[e];
    int pos = atomicAdd(&cur[v >> 8], 1);
    out[pos] = v;
  }
}

// per-src-bucket 256-bin LDS histogram -> deg_out
__global__ __launch_bounds__(256) void buckethist_kernel(const int* __restrict__ sorted,
                                                         const int* __restrict__ hist_t,
                                                         int* __restrict__ deg_out) {
  __shared__ int h[256];
  int b = blockIdx.x, t = threadIdx.x;
  int p0 = hist_t[b * NC];
  int p1 = (b == NB - 1) ? EE : hist_t[(b + 1) * NC];
  h[t] = 0;
  __syncthreads();
  for (int i = p0 + t; i < p1; i += 256) atomicAdd(&h[sorted[i] & 255], 1);
  __syncthreads();
  int n = (b << 8) + t;
  if (n < NN) deg_out[n] = h[t];
}

__global__ void feature_kernel(const int* __restrict__ row_ptr, const int* __restrict__ deg_out,
                               float* __restrict__ norm_src, float* __restrict__ norm_dst,
                               float4* __restrict__ xs1) {
  int n = blockIdx.x * blockDim.x + threadIdx.x;
  if (n >= NN) return;
  int dii = row_ptr[n + 1] - row_ptr[n];
  int doo = deg_out[n];
  float di = (float)dii;
  float dofl = (float)doo;
  float ns = rsqrtf(fmaxf(dofl, 1.0f));
  float nd = rsqrtf(fmaxf(di, 1.0f));
  norm_src[n] = ns;
  norm_dst[n] = nd;
  float h1 = di;
  float h2 = (di - 3.0f > 0.0f) ? 1.0f : 0.0f;
  float h3 = 3.0f / di;
  float h4 = (di - 4.0f > 0.0f) ? 1.0f : 0.0f;
  float4 o;
  o.x = h1 * ns; o.y = h2 * ns; o.z = h3 * ns; o.w = h4 * ns;
  xs1[n] = o;
}

__global__ void spmm4_kernel(const int* __restrict__ rp, const int* __restrict__ col,
                             const float4* __restrict__ xs1, const float* __restrict__ norm_dst,
                             float4* __restrict__ agg4) {
  int n = blockIdx.x * blockDim.x + threadIdx.x;
  if (n >= NN) return;
  int e0 = rp[n], e1 = rp[n + 1];
  float ax = 0.f, ay = 0.f, az = 0.f, aw = 0.f;
  for (int e = e0; e < e1; ++e) {
    int s = __builtin_nontemporal_load(&col[e]);
    float4 v = xs1[s];
    ax += v.x; ay += v.y; az += v.z; aw += v.w;
  }
  float nd = norm_dst[n];
  float4 o; o.x = ax * nd; o.y = ay * nd; o.z = az * nd; o.w = aw * nd;
  agg4[n] = o;
}

__device__ __forceinline__ void acc_row(uint2 v, float& a0, float& a1, float& a2, float& a3) {
  __half2 h0 = *reinterpret_cast<__half2*>(&v.x);
  __half2 h1 = *reinterpret_cast<__half2*>(&v.y);
  float2 f0 = __half22float2(h0);
  float2 f1 = __half22float2(h1);
  a0 += f0.x; a1 += f0.y; a2 += f1.x; a3 += f1.y;
}

// one wave per dst row (layer-5 spmm); 16x unrolled; f16 out
__global__ __launch_bounds__(256) void spmm256_kernel(
    const int* __restrict__ rp, const int* __restrict__ col,
    const __half* __restrict__ hs, const float* __restrict__ norm_dst,
    __half* __restrict__ aggH) {
  int wid = (blockIdx.x * blockDim.x + threadIdx.x) >> 6;
  int lane = threadIdx.x & 63;
  if (wid >= NN) return;
  int e0 = rp[wid], e1 = rp[wid + 1];
  float a0 = 0.f, a1 = 0.f, a2 = 0.f, a3 = 0.f;
  const __half* hp = hs + lane * 4;
  int e = e0;
  for (; e + 16 <= e1; e += 16) {
    int s[16];
#pragma unroll
    for (int u = 0; u < 16; ++u)
      s[u] = __builtin_amdgcn_readfirstlane(__builtin_nontemporal_load(&col[e + u]));
    uint2 v[16];
#pragma unroll
    for (int u = 0; u < 16; ++u) v[u] = *(const uint2*)(hp + (size_t)s[u] * HH);
#pragma unroll
    for (int u = 0; u < 16; ++u) acc_row(v[u], a0, a1, a2, a3);
  }
  for (; e + 4 <= e1; e += 4) {
    int s[4];
#pragma unroll
    for (int u = 0; u < 4; ++u)
      s[u] = __builtin_amdgcn_readfirstlane(__builtin_nontemporal_load(&col[e + u]));
    uint2 v[4];
#pragma unroll
    for (int u = 0; u < 4; ++u) v[u] = *(const uint2*)(hp + (size_t)s[u] * HH);
#pragma unroll
    for (int u = 0; u < 4; ++u) acc_row(v[u], a0, a1, a2, a3);
  }
  for (; e < e1; ++e) {
    int s = __builtin_amdgcn_readfirstlane(__builtin_nontemporal_load(&col[e]));
    uint2 v = *(const uint2*)(hp + (size_t)s * HH);
    acc_row(v, a0, a1, a2, a3);
  }
  float nd = norm_dst[wid];
  __half2 p0 = __floats2half2_rn(a0 * nd, a1 * nd);
  __half2 p1 = __floats2half2_rn(a2 * nd, a3 * nd);
  uintx2 o;
  o[0] = *(unsigned*)&p0;
  o[1] = *(unsigned*)&p1;
  __builtin_nontemporal_store(o, (uintx2*)(aggH + (size_t)wid * HH + lane * 4));
}

// FUSED spmm+gemm: gather 64 dst rows into LDS, then MFMA + tanh + norm_src -> hs_out
__global__ __launch_bounds__(256, 4) void fused_kernel(
    const int* __restrict__ rp, const int* __restrict__ col,
    const __half* __restrict__ hs, const float* __restrict__ norm_dst,
    const __half* __restrict__ Wf, const float* __restrict__ bias,
    const float* __restrict__ norm_src, __half* __restrict__ hs_out) {
  __shared__ __half tileA[64 * LP];
  int t = threadIdx.x;
  int w = t >> 6, lane = t & 63;
  int row0 = blockIdx.x * 64;
  const __half* hp = hs + lane * 4;

  // gather phase: wave w handles rows row0 + w*16 .. +15
  for (int r = 0; r < 16; ++r) {
    int row = row0 + w * 16 + r;
    int e0 = rp[row], e1 = rp[row + 1];
    float a0 = 0.f, a1 = 0.f, a2 = 0.f, a3 = 0.f;
    int e = e0;
    for (; e + 8 <= e1; e += 8) {
      int s[8];
#pragma unroll
      for (int u = 0; u < 8; ++u)
        s[u] = __builtin_amdgcn_readfirstlane(__builtin_nontemporal_load(&col[e + u]));
      uint2 v[8];
#pragma unroll
      for (int u = 0; u < 8; ++u) v[u] = *(const uint2*)(hp + (size_t)s[u] * HH);
#pragma unroll
      for (int u = 0; u < 8; ++u) acc_row(v[u], a0, a1, a2, a3);
    }
    for (; e < e1; ++e) {
      int s = __builtin_amdgcn_readfirstlane(__builtin_nontemporal_load(&col[e]));
      uint2 v = *(const uint2*)(hp + (size_t)s * HH);
      acc_row(v, a0, a1, a2, a3);
    }
    float nd = norm_dst[row];
    __half2 p0 = __floats2half2_rn(a0 * nd, a1 * nd);
    __half2 p1 = __floats2half2_rn(a2 * nd, a3 * nd);
    unsigned* dst = (unsigned*)(tileA + (w * 16 + r) * LP + lane * 4);
    dst[0] = *(unsigned*)&p0;
    dst[1] = *(unsigned*)&p1;
  }
  __syncthreads();

  // MFMA phase (identical fragment layout to gemm_mfma, A from LDS)
  int l15 = lane & 15, l4 = lane >> 4;
  floatx4 acc[4][4];
#pragma unroll
  for (int m = 0; m < 4; ++m)
#pragma unroll
    for (int n = 0; n < 4; ++n) acc[m][n] = (floatx4)(0.0f);

#pragma unroll
  for (int ks = 0; ks < 8; ++ks) {
    int k0 = ks * 32 + l4 * 8;
    half8 af[4];
#pragma unroll
    for (int m = 0; m < 4; ++m)
      af[m] = *(const half8*)(tileA + (m * 16 + l15) * LP + k0);
    half8 bf[4];
#pragma unroll
    for (int n = 0; n < 4; ++n)
      bf[n] = *(const half8*)(Wf + ((size_t)(ks * 16 + w * 4 + n) * 64 + lane) * 8);
#pragma unroll
    for (int m = 0; m < 4; ++m)
#pragma unroll
      for (int n = 0; n < 4; ++n)
        acc[m][n] = __builtin_amdgcn_mfma_f32_16x16x32_f16(af[m], bf[n], acc[m][n], 0, 0, 0);
  }

  float ns[16];
#pragma unroll
  for (int m = 0; m < 4; ++m)
#pragma unroll
    for (int r = 0; r < 4; ++r) ns[m * 4 + r] = norm_src[row0 + m * 16 + l4 * 4 + r];
#pragma unroll
  for (int n = 0; n < 4; ++n) {
    int c = w * 64 + n * 16 + l15;
    float bb = bias[c];
#pragma unroll
    for (int m = 0; m < 4; ++m) {
#pragma unroll
      for (int r = 0; r < 4; ++r) {
        int row = row0 + m * 16 + l4 * 4 + r;
        float y = fast_tanh(acc[m][n][r] + bb);
        hs_out[(size_t)row * HH + c] = (__half)(y * ns[m * 4 + r]);
      }
    }
  }
}

// layer-1 transform (K=4), VALU path
__global__ __launch_bounds__(256) void transform4_kernel(
    const float* __restrict__ agg, const float* __restrict__ W, const float* __restrict__ b,
    const float* __restrict__ norm_src, __half* __restrict__ hs_out) {
  __shared__ float tile[64 * 4];
  int t = threadIdx.x;
  int rowbase = blockIdx.x * 64;
  const float4* srcp = (const float4*)(agg + (size_t)rowbase * 4);
  float4* dst4 = (float4*)tile;
  for (int i = t; i < 64; i += 256) dst4[i] = srcp[i];
  __syncthreads();
  int w = t >> 6, lane = t & 63;
  int c0 = lane * 4;
  float acc[16][4];
#pragma unroll
  for (int r = 0; r < 16; ++r) {
    acc[r][0] = 0.f; acc[r][1] = 0.f; acc[r][2] = 0.f; acc[r][3] = 0.f;
  }
  const float* tw = tile + (size_t)(w * 16) * 4;
#pragma unroll
  for (int k = 0; k < 4; ++k) {
    float4 wv = *(const float4*)(W + (size_t)k * HH + c0);
#pragma unroll
    for (int r = 0; r < 16; ++r) {
      float a = tw[r * 4 + k];
      acc[r][0] += a * wv.x;
      acc[r][1] += a * wv.y;
      acc[r][2] += a * wv.z;
      acc[r][3] += a * wv.w;
    }
  }
  float4 bv = *(const float4*)(b + c0);
#pragma unroll
  for (int r = 0; r < 16; ++r) {
    int row = rowbase + w * 16 + r;
    float ns = norm_src[row];
    float y0 = fast_tanh(acc[r][0] + bv.x) * ns;
    float y1 = fast_tanh(acc[r][1] + bv.y) * ns;
    float y2 = fast_tanh(acc[r][2] + bv.z) * ns;
    float y3 = fast_tanh(acc[r][3] + bv.w) * ns;
    __half2 p0 = __floats2half2_rn(y0, y1);
    __half2 p1 = __floats2half2_rn(y2, y3);
    uint2 o = make_uint2(*(unsigned*)&p0, *(unsigned*)&p1);
    *(uint2*)(hs_out + (size_t)row * HH + c0) = o;
  }
}

// repack all 4 W [256,256] fp32 row-major into fragment-contiguous f16
__global__ void repack_w_kernel(const float* __restrict__ W2, const float* __restrict__ W3,
                                const float* __restrict__ W4, const float* __restrict__ W5,
                                __half* __restrict__ Wf) {
  int t = blockIdx.x * blockDim.x + threadIdx.x;  // 4*65536 threads
  int which = t >> 16;
  int u = t & 65535;
  const float* W = (which == 0) ? W2 : (which == 1) ? W3 : (which == 2) ? W4 : W5;
  int b = u & 7;
  int lane = (u >> 3) & 63;
  int tile = (u >> 9) & 15;
  int ks = u >> 13;
  int k = ks * 32 + (lane >> 4) * 8 + b;
  int c = tile * 16 + (lane & 15);
  Wf[t] = __float2half(W[k * HH + c]);
}

// MFMA transform (layer 5): out = tanh(aggH @ W + b) -> fp32 h
__global__ __launch_bounds__(256) void gemm_mfma_kernel(
    const __half* __restrict__ aggH, const __half* __restrict__ Wf,
    const float* __restrict__ bias, float* __restrict__ h_out) {
  int w = threadIdx.x >> 6;
  int lane = threadIdx.x & 63;
  int l15 = lane & 15, l4 = lane >> 4;
  int row0 = blockIdx.x * 64;
  floatx4 acc[4][4];
#pragma unroll
  for (int m = 0; m < 4; ++m)
#pragma unroll
    for (int n = 0; n < 4; ++n) acc[m][n] = (floatx4)(0.0f);

#pragma unroll
  for (int ks = 0; ks < 8; ++ks) {
    int k0 = ks * 32 + l4 * 8;
    half8 af[4];
#pragma unroll
    for (int m = 0; m < 4; ++m)
      af[m] = *(const half8*)(aggH + (size_t)(row0 + m * 16 + l15) * HH + k0);
    half8 bf[4];
#pragma unroll
    for (int n = 0; n < 4; ++n)
      bf[n] = *(const half8*)(Wf + ((size_t)(ks * 16 + w * 4 + n) * 64 + lane) * 8);
#pragma unroll
    for (int m = 0; m < 4; ++m)
#pragma unroll
      for (int n = 0; n < 4; ++n)
        acc[m][n] = __builtin_amdgcn_mfma_f32_16x16x32_f16(af[m], bf[n], acc[m][n], 0, 0, 0);
  }

#pragma unroll
  for (int n = 0; n < 4; ++n) {
    int c = w * 64 + n * 16 + l15;
    float bb = bias[c];
#pragma unroll
    for (int m = 0; m < 4; ++m) {
#pragma unroll
      for (int r = 0; r < 4; ++r) {
        int row = row0 + m * 16 + l4 * 4 + r;
        h_out[(size_t)row * HH + c] = fast_tanh(acc[m][n][r] + bb);
      }
    }
  }
}

__global__ void mean_kernel(const float* __restrict__ h, const int* __restrict__ g_ptr,
                            float* __restrict__ emb) {
  int g = blockIdx.x;
  int j = threadIdx.x;  // 256 threads
  int s = g_ptr[g], e = g_ptr[g + 1];
  float sum = 0.f;
  for (int n = s; n < e; ++n) sum += h[(size_t)n * HH + j];
  int cnt = e - s;
  emb[(size_t)g * HH + j] = (cnt > 0) ? sum / (float)cnt : 0.0f;
}

__global__ __launch_bounds__(128) void mlp_kernel(const float* __restrict__ emb,
                                                  const float* __restrict__ Wl1,
                                                  const float* __restrict__ bl1,
                                                  const float* __restrict__ Wl2,
                                                  const float* __restrict__ bl2,
                                                  float* __restrict__ pred) {
  __shared__ float se[256];
  __shared__ float sh[128];
  int g = blockIdx.x, t = threadIdx.x;
  se[t] = emb[(size_t)g * HH + t];
  se[t + 128] = emb[(size_t)g * HH + t + 128];
  __syncthreads();
  float acc = bl1[t];
  for (int k = 0; k < 256; ++k) acc += se[k] * Wl1[k * 128 + t];
  float he = (acc > 0.f) ? acc : 0.01f * acc;
  sh[t] = he * Wl2[t];
  __syncthreads();
  if (t < 64) sh[t] += sh[t + 64];
  __syncthreads();
  if (t < 64) {
    float v = sh[t];
    for (int off = 32; off > 0; off >>= 1) v += __shfl_down(v, off);
    if (t == 0) {
      float z = v + bl2[0];
      pred[g] = 1.0f / (1.0f + expf(-z));
    }
  }
}

extern "C" void kernel_launch(void* const* d_in, const int* in_sizes, int n_in,
                              void* d_out, int out_size, void* d_ws, size_t ws_size,
                              hipStream_t stream) {
  const int* src = (const int*)d_in[0];
  const int* dst = (const int*)d_in[1];
  const int* gid = (const int*)d_in[2];
  const float* W1 = (const float*)d_in[3];
  const float* b1 = (const float*)d_in[4];
  const float* W2 = (const float*)d_in[5];
  const float* b2 = (const float*)d_in[6];
  const float* W3 = (const float*)d_in[7];
  const float* b3 = (const float*)d_in[8];
  const float* W4 = (const float*)d_in[9];
  const float* b4 = (const float*)d_in[10];
  const float* W5 = (const float*)d_in[11];
  const float* b5 = (const float*)d_in[12];
  const float* Wl1 = (const float*)d_in[13];
  const float* bl1 = (const float*)d_in[14];
  const float* Wl2 = (const float*)d_in[15];
  const float* bl2 = (const float*)d_in[16];

  char* ws = (char*)d_ws;
  size_t off = 0;
  auto alloc = [&](size_t bytes) -> void* {
    void* p = ws + off;
    off += (bytes + 255) & ~(size_t)255;
    return p;
  };

  int* col = (int*)alloc((size_t)EE * 4);
  int* row_ptr = (int*)alloc((size_t)(NN + 1) * 4);
  int* hist_t = (int*)alloc((size_t)NB * NC * 4);
  int* bucket_ptr = (int*)alloc((size_t)(NB + 1) * 4);
  int* bsum = (int*)alloc(1024 * 4);
  int* boffs = (int*)alloc(1025 * 4);
  int* g_ptr = (int*)alloc((size_t)(GG + 1) * 4);
  int* deg_out = (int*)alloc((size_t)NN * 4);
  float* norm_src = (float*)alloc((size_t)NN * 4);
  float* norm_dst = (float*)alloc((size_t)NN * 4);
  float4* xs1 = (float4*)alloc((size_t)NN * 16);
  float4* agg4 = (float4*)alloc((size_t)NN * 16);
  __half* Wf = (__half*)alloc((size_t)4 * HH * HH * 2);
  // union area (102.4 MB): pairs -> src_sorted -> hsA -> aggH (disjoint lifetimes)
  void* unionp = alloc((size_t)NN * HH * 2);
  uint2* pairs = (uint2*)unionp;
  int* src_sorted = (int*)unionp;
  __half* hsA = (__half*)unionp;
  __half* aggH = (__half*)unionp;

  float* outp = (float*)d_out;
  float* pred = outp;
  float* emb = outp + GG;
  float* hreg = outp + GG + (size_t)GG * HH;  // final h fp32 (fully written at layer 5)
  __half* hsB = (__half*)hreg;                // f16 ping buffer in d_out h region

  gptr_kernel<<<(NN + 255) / 256, 256, 0, stream>>>(gid, g_ptr);
  repack_w_kernel<<<1024, 256, 0, stream>>>(W2, W3, W4, W5, Wf);

  const int nscan = NB * NC;                  // 611,524
  const int nbA = (nscan + 1023) / 1024;      // 598
  // dst bucket sort -> col, row_ptr
  hist1_kernel<<<NC, 256, 0, stream>>>(dst, hist_t);
  scanA4_kernel<<<nbA, 256, 0, stream>>>(hist_t, nscan, bsum);
  scanB_kernel<<<1, 1024, 0, stream>>>(bsum, nbA, boffs);
  addC4_kernel<<<(nscan + 255) / 256, 256, 0, stream>>>(hist_t, nscan, boffs);
  bucketptr_kernel<<<(NB + 256) / 256, 256, 0, stream>>>(hist_t, bucket_ptr);
  scatter1_kernel<<<NC, 256, 0, stream>>>(src, dst, hist_t, pairs);
  bucket_kernel<<<NB, 256, 0, stream>>>(pairs, bucket_ptr, col, row_ptr);

  // src bucket sort -> deg_out (pairs dead; reuse hist_t and union area)
  hist1_kernel<<<NC, 256, 0, stream>>>(src, hist_t);
  scanA4_kernel<<<nbA, 256, 0, stream>>>(hist_t, nscan, bsum);
  scanB_kernel<<<1, 1024, 0, stream>>>(bsum, nbA, boffs);
  addC4_kernel<<<(nscan + 255) / 256, 256, 0, stream>>>(hist_t, nscan, boffs);
  scatter_src_kernel<<<NC, 256, 0, stream>>>(src, hist_t, src_sorted);
  buckethist_kernel<<<NB, 256, 0, stream>>>(src_sorted, hist_t, deg_out);

  feature_kernel<<<(NN + 255) / 256, 256, 0, stream>>>(row_ptr, deg_out, norm_src, norm_dst, xs1);

  // layer 1 (K=4)
  spmm4_kernel<<<(NN + 255) / 256, 256, 0, stream>>>(row_ptr, col, xs1, norm_dst, agg4);
  transform4_kernel<<<NN / 64, 256, 0, stream>>>((const float*)agg4, W1, b1, norm_src, hsA);

  // layers 2-4 fused (ping-pong hsA <-> hsB)
  fused_kernel<<<NN / 64, 256, 0, stream>>>(row_ptr, col, hsA, norm_dst,
                                            Wf + 0 * HH * HH, b2, norm_src, hsB);
  fused_kernel<<<NN / 64, 256, 0, stream>>>(row_ptr, col, hsB, norm_dst,
                                            Wf + 1 * (size_t)HH * HH, b3, norm_src, hsA);
  fused_kernel<<<NN / 64, 256, 0, stream>>>(row_ptr, col, hsA, norm_dst,
                                            Wf + 2 * (size_t)HH * HH, b4, norm_src, hsB);

  // layer 5 split: spmm -> aggH (union; hsA dead), gemm -> fp32 h (overwrites hsB region)
  spmm256_kernel<<<NN / 4, 256, 0, stream>>>(row_ptr, col, hsB, norm_dst, aggH);
  gemm_mfma_kernel<<<NN / 64, 256, 0, stream>>>(aggH, Wf + 3 * (size_t)HH * HH, b5, hreg);

  mean_kernel<<<GG, 256, 0, stream>>>(hreg, g_ptr, emb);
  mlp_kernel<<<GG, 128, 0, stream>>>(emb, Wl1, bl1, Wl2, bl2, pred);
}

// Round 9
// 2831.117 us; speedup vs baseline: 1.0644x; 1.0486x over previous
//
#include <hip/hip_runtime.h>
#include <hip/hip_fp16.h>

#define NN 200000
#define EE 6400000
#define GG 1024
#define HH 256
#define NB 782        // buckets = ceil(NN/256)
#define NC 782        // edge chunks = ceil(EE/8192)
#define CHUNK 8192
#define CAP 9216      // LDS stage capacity per bucket

typedef _Float16 half8 __attribute__((ext_vector_type(8)));
typedef float floatx4 __attribute__((ext_vector_type(4)));
typedef unsigned int uintx2 __attribute__((ext_vector_type(2)));

__device__ __forceinline__ float fast_tanh(float x) {
  float e = __expf(2.0f * x);
  return 1.0f - 2.0f / (e + 1.0f);
}

// g_ptr from sorted gid boundaries
__global__ void gptr_kernel(const int* __restrict__ gid, int* __restrict__ g_ptr) {
  int n = blockIdx.x * blockDim.x + threadIdx.x;
  if (n >= NN) return;
  int g = gid[n];
  int gp = (n == 0) ? -1 : gid[n - 1];
  for (int x = gp + 1; x <= g; ++x) g_ptr[x] = n;
  if (n == NN - 1) {
    for (int x = g + 1; x <= GG; ++x) g_ptr[x] = NN;
  }
}

// per-chunk bucket counts of dst AND src in one pass, bucket-major outputs
__global__ __launch_bounds__(256) void hist_dual_kernel(const int* __restrict__ dst,
                                                        const int* __restrict__ src,
                                                        int* __restrict__ hist_d,
                                                        int* __restrict__ hist_s) {
  __shared__ int hd[NB];
  __shared__ int hsb[NB];
  int c = blockIdx.x, t = threadIdx.x;
  for (int b = t; b < NB; b += 256) { hd[b] = 0; hsb[b] = 0; }
  __syncthreads();
  int e0 = c * CHUNK, e1 = min(e0 + CHUNK, EE);
  for (int e = e0 + t; e < e1; e += 256) {
    atomicAdd(&hd[dst[e] >> 8], 1);
    atomicAdd(&hsb[src[e] >> 8], 1);
  }
  __syncthreads();
  for (int b = t; b < NB; b += 256) {
    hist_d[b * NC + c] = hd[b];
    hist_s[b * NC + c] = hsb[b];
  }
}

// scan stage A: 1024 elems/block (4/thread), in-place exclusive, emits block sums
__global__ __launch_bounds__(256) void scanA4_kernel(int* __restrict__ a, int n,
                                                     int* __restrict__ bsum) {
  __shared__ int ws4[4];
  int t = threadIdx.x;
  int base = blockIdx.x * 1024 + t * 4;
  int v0 = 0, v1 = 0, v2 = 0, v3 = 0;
  if (base + 3 < n) {
    int4 q = *(const int4*)(a + base);
    v0 = q.x; v1 = q.y; v2 = q.z; v3 = q.w;
  } else {
    if (base + 0 < n) v0 = a[base + 0];
    if (base + 1 < n) v1 = a[base + 1];
    if (base + 2 < n) v2 = a[base + 2];
    if (base + 3 < n) v3 = a[base + 3];
  }
  int s = v0 + v1 + v2 + v3;
  int lane = t & 63, w = t >> 6;
  int x = s;
  for (int off = 1; off < 64; off <<= 1) {
    int y = __shfl_up(x, off);
    if (lane >= off) x += y;
  }
  if (lane == 63) ws4[w] = x;
  __syncthreads();
  if (t == 0) {
    int acc = 0;
    for (int k = 0; k < 4; ++k) { int tmp = ws4[k]; ws4[k] = acc; acc += tmp; }
  }
  __syncthreads();
  int e = ws4[w] + x - s;
  int o0 = e, o1 = e + v0, o2 = o1 + v1, o3 = o2 + v2;
  if (base + 3 < n) {
    int4 q; q.x = o0; q.y = o1; q.z = o2; q.w = o3;
    *(int4*)(a + base) = q;
  } else {
    if (base + 0 < n) a[base + 0] = o0;
    if (base + 1 < n) a[base + 1] = o1;
    if (base + 2 < n) a[base + 2] = o2;
    if (base + 3 < n) a[base + 3] = o3;
  }
  if (t == 255) bsum[blockIdx.x] = ws4[3] + x;
}

// stage B: single-block exclusive scan of block sums (nb <= 1024)
__global__ __launch_bounds__(1024) void scanB_kernel(const int* __restrict__ bsum, int nb,
                                                     int* __restrict__ boffs) {
  __shared__ int wsum[16];
  int t = threadIdx.x;
  int lane = t & 63, w = t >> 6;
  int v = (t < nb) ? bsum[t] : 0;
  int x = v;
  for (int off = 1; off < 64; off <<= 1) {
    int y = __shfl_up(x, off);
    if (lane >= off) x += y;
  }
  if (lane == 63) wsum[w] = x;
  __syncthreads();
  if (t < 16) {
    int s = wsum[t];
    for (int off = 1; off < 16; off <<= 1) {
      int y = __shfl_up(s, off);
      if (t >= off) s += y;
    }
    wsum[t] = s;
  }
  __syncthreads();
  int waveoff = (w > 0) ? wsum[w - 1] : 0;
  int excl = waveoff + (x - v);
  if (t <= nb) boffs[t] = excl;
}

__global__ void addC4_kernel(int* __restrict__ a, int n, const int* __restrict__ boffs) {
  int i = blockIdx.x * blockDim.x + threadIdx.x;
  if (i < n) a[i] += boffs[i >> 10];
}

// pass-1 scatter: edges -> packed keys ((d&255)<<24 | src) grouped by dst-bucket
__global__ __launch_bounds__(256) void scatter1_kernel(const int* __restrict__ src,
                                                       const int* __restrict__ dst,
                                                       const int* __restrict__ hist_d,
                                                       unsigned* __restrict__ keys) {
  __shared__ int cur[NB];
  int c = blockIdx.x, t = threadIdx.x;
  for (int b = t; b < NB; b += 256) cur[b] = hist_d[b * NC + c];
  __syncthreads();
  int e0 = c * CHUNK, e1 = min(e0 + CHUNK, EE);
  for (int e = e0 + t; e < e1; e += 256) {
    int d = dst[e], s = src[e];
    int pos = atomicAdd(&cur[d >> 8], 1);
    keys[pos] = ((unsigned)(d & 255) << 24) | (unsigned)s;
  }
}

// pass-2: per-bucket counting sort in LDS; emits col (coalesced) + row_ptr
__global__ __launch_bounds__(256) void bucket_kernel(const unsigned* __restrict__ keys,
                                                     const int* __restrict__ hist_d,
                                                     int* __restrict__ col,
                                                     int* __restrict__ row_ptr) {
  __shared__ int rhist[256];
  __shared__ int rcur[256];
  __shared__ int ws4[4];
  __shared__ int stage[CAP];
  int b = blockIdx.x, t = threadIdx.x;
  int row0 = b << 8;
  int p0 = hist_d[b * NC];
  int p1 = (b == NB - 1) ? EE : hist_d[(b + 1) * NC];
  int cnt = p1 - p0;
  rhist[t] = 0;
  __syncthreads();
  for (int i = t; i < cnt; i += 256) {
    atomicAdd(&rhist[keys[p0 + i] >> 24], 1);
  }
  __syncthreads();
  int v = rhist[t];
  int lane = t & 63, w = t >> 6;
  int x = v;
  for (int off = 1; off < 64; off <<= 1) {
    int y = __shfl_up(x, off);
    if (lane >= off) x += y;
  }
  if (lane == 63) ws4[w] = x;
  __syncthreads();
  if (t == 0) {
    int acc = 0;
    for (int k = 0; k < 4; ++k) { int tmp = ws4[k]; ws4[k] = acc; acc += tmp; }
  }
  __syncthreads();
  int excl = ws4[w] + x - v;
  rcur[t] = excl;
  int row = row0 + t;
  if (row < NN) row_ptr[row] = p0 + excl;
  if (b == NB - 1 && t == 0) row_ptr[NN] = EE;
  __syncthreads();
  for (int i = t; i < cnt; i += 256) {
    unsigned k = keys[p0 + i];
    int pos = atomicAdd(&rcur[k >> 24], 1);
    int s = (int)(k & 0xFFFFFFu);
    if (pos < CAP) stage[pos] = s;
    else col[p0 + pos] = s;  // overflow guard (statistically never)
  }
  __syncthreads();
  int lim = min(cnt, CAP);
  for (int i = t; i < lim; i += 256) col[p0 + i] = stage[i];
}

// scatter src values grouped by src-bucket (payload = value itself)
__global__ __launch_bounds__(256) void scatter_src_kernel(const int* __restrict__ src,
                                                          const int* __restrict__ hist_s,
                                                          int* __restrict__ out) {
  __shared__ int cur[NB];
  int c = blockIdx.x, t = threadIdx.x;
  for (int b = t; b < NB; b += 256) cur[b] = hist_s[b * NC + c];
  __syncthreads();
  int e0 = c * CHUNK, e1 = min(e0 + CHUNK, EE);
  for (int e = e0 + t; e < e1; e += 256) {
    int v = src[e];
    int pos = atomicAdd(&cur[v >> 8], 1);
    out[pos] = v;
  }
}

// per-src-bucket 256-bin LDS histogram -> deg_out
__global__ __launch_bounds__(256) void buckethist_kernel(const int* __restrict__ sorted,
                                                         const int* __restrict__ hist_s,
                                                         int* __restrict__ deg_out) {
  __shared__ int h[256];
  int b = blockIdx.x, t = threadIdx.x;
  int p0 = hist_s[b * NC];
  int p1 = (b == NB - 1) ? EE : hist_s[(b + 1) * NC];
  h[t] = 0;
  __syncthreads();
  for (int i = p0 + t; i < p1; i += 256) atomicAdd(&h[sorted[i] & 255], 1);
  __syncthreads();
  int n = (b << 8) + t;
  if (n < NN) deg_out[n] = h[t];
}

__global__ void feature_kernel(const int* __restrict__ row_ptr, const int* __restrict__ deg_out,
                               float* __restrict__ norm_src, float* __restrict__ norm_dst,
                               float4* __restrict__ xs1) {
  int n = blockIdx.x * blockDim.x + threadIdx.x;
  if (n >= NN) return;
  int dii = row_ptr[n + 1] - row_ptr[n];
  int doo = deg_out[n];
  float di = (float)dii;
  float dofl = (float)doo;
  float ns = rsqrtf(fmaxf(dofl, 1.0f));
  float nd = rsqrtf(fmaxf(di, 1.0f));
  norm_src[n] = ns;
  norm_dst[n] = nd;
  float h1 = di;
  float h2 = (di - 3.0f > 0.0f) ? 1.0f : 0.0f;
  float h3 = 3.0f / di;
  float h4 = (di - 4.0f > 0.0f) ? 1.0f : 0.0f;
  float4 o;
  o.x = h1 * ns; o.y = h2 * ns; o.z = h3 * ns; o.w = h4 * ns;
  xs1[n] = o;
}

__global__ void spmm4_kernel(const int* __restrict__ rp, const int* __restrict__ col,
                             const float4* __restrict__ xs1, const float* __restrict__ norm_dst,
                             float4* __restrict__ agg4) {
  int n = blockIdx.x * blockDim.x + threadIdx.x;
  if (n >= NN) return;
  int e0 = rp[n], e1 = rp[n + 1];
  float ax = 0.f, ay = 0.f, az = 0.f, aw = 0.f;
  for (int e = e0; e < e1; ++e) {
    int s = __builtin_nontemporal_load(&col[e]);
    float4 v = xs1[s];
    ax += v.x; ay += v.y; az += v.z; aw += v.w;
  }
  float nd = norm_dst[n];
  float4 o; o.x = ax * nd; o.y = ay * nd; o.z = az * nd; o.w = aw * nd;
  agg4[n] = o;
}

__device__ __forceinline__ void acc_row(uint2 v, float& a0, float& a1, float& a2, float& a3) {
  __half2 h0 = *reinterpret_cast<__half2*>(&v.x);
  __half2 h1 = *reinterpret_cast<__half2*>(&v.y);
  float2 f0 = __half22float2(h0);
  float2 f1 = __half22float2(h1);
  a0 += f0.x; a1 += f0.y; a2 += f1.x; a3 += f1.y;
}

// one wave per dst row; lane holds 4 features; 16x unrolled; scalar gathers; f16 out
__global__ __launch_bounds__(256) void spmm256_kernel(
    const int* __restrict__ rp, const int* __restrict__ col,
    const __half* __restrict__ hs, const float* __restrict__ norm_dst,
    __half* __restrict__ aggH) {
  int wid = (blockIdx.x * blockDim.x + threadIdx.x) >> 6;
  int lane = threadIdx.x & 63;
  if (wid >= NN) return;
  int e0 = rp[wid], e1 = rp[wid + 1];
  float a0 = 0.f, a1 = 0.f, a2 = 0.f, a3 = 0.f;
  const __half* hp = hs + lane * 4;
  int e = e0;
  for (; e + 16 <= e1; e += 16) {
    int s[16];
#pragma unroll
    for (int u = 0; u < 16; ++u)
      s[u] = __builtin_amdgcn_readfirstlane(__builtin_nontemporal_load(&col[e + u]));
    uint2 v[16];
#pragma unroll
    for (int u = 0; u < 16; ++u) v[u] = *(const uint2*)(hp + (size_t)s[u] * HH);
#pragma unroll
    for (int u = 0; u < 16; ++u) acc_row(v[u], a0, a1, a2, a3);
  }
  for (; e + 4 <= e1; e += 4) {
    int s[4];
#pragma unroll
    for (int u = 0; u < 4; ++u)
      s[u] = __builtin_amdgcn_readfirstlane(__builtin_nontemporal_load(&col[e + u]));
    uint2 v[4];
#pragma unroll
    for (int u = 0; u < 4; ++u) v[u] = *(const uint2*)(hp + (size_t)s[u] * HH);
#pragma unroll
    for (int u = 0; u < 4; ++u) acc_row(v[u], a0, a1, a2, a3);
  }
  for (; e < e1; ++e) {
    int s = __builtin_amdgcn_readfirstlane(__builtin_nontemporal_load(&col[e]));
    uint2 v = *(const uint2*)(hp + (size_t)s * HH);
    acc_row(v, a0, a1, a2, a3);
  }
  float nd = norm_dst[wid];
  __half2 p0 = __floats2half2_rn(a0 * nd, a1 * nd);
  __half2 p1 = __floats2half2_rn(a2 * nd, a3 * nd);
  uintx2 o;
  o[0] = *(unsigned*)&p0;
  o[1] = *(unsigned*)&p1;
  __builtin_nontemporal_store(o, (uintx2*)(aggH + (size_t)wid * HH + lane * 4));
}

// layer-1 transform (K=4), VALU path
__global__ __launch_bounds__(256) void transform4_kernel(
    const float* __restrict__ agg, const float* __restrict__ W, const float* __restrict__ b,
    const float* __restrict__ norm_src, __half* __restrict__ hs_out) {
  __shared__ float tile[64 * 4];
  int t = threadIdx.x;
  int rowbase = blockIdx.x * 64;
  const float4* srcp = (const float4*)(agg + (size_t)rowbase * 4);
  float4* dst4 = (float4*)tile;
  for (int i = t; i < 64; i += 256) dst4[i] = srcp[i];
  __syncthreads();
  int w = t >> 6, lane = t & 63;
  int c0 = lane * 4;
  float acc[16][4];
#pragma unroll
  for (int r = 0; r < 16; ++r) {
    acc[r][0] = 0.f; acc[r][1] = 0.f; acc[r][2] = 0.f; acc[r][3] = 0.f;
  }
  const float* tw = tile + (size_t)(w * 16) * 4;
#pragma unroll
  for (int k = 0; k < 4; ++k) {
    float4 wv = *(const float4*)(W + (size_t)k * HH + c0);
#pragma unroll
    for (int r = 0; r < 16; ++r) {
      float a = tw[r * 4 + k];
      acc[r][0] += a * wv.x;
      acc[r][1] += a * wv.y;
      acc[r][2] += a * wv.z;
      acc[r][3] += a * wv.w;
    }
  }
  float4 bv = *(const float4*)(b + c0);
#pragma unroll
  for (int r = 0; r < 16; ++r) {
    int row = rowbase + w * 16 + r;
    float ns = norm_src[row];
    float y0 = fast_tanh(acc[r][0] + bv.x) * ns;
    float y1 = fast_tanh(acc[r][1] + bv.y) * ns;
    float y2 = fast_tanh(acc[r][2] + bv.z) * ns;
    float y3 = fast_tanh(acc[r][3] + bv.w) * ns;
    __half2 p0 = __floats2half2_rn(y0, y1);
    __half2 p1 = __floats2half2_rn(y2, y3);
    uint2 o = make_uint2(*(unsigned*)&p0, *(unsigned*)&p1);
    *(uint2*)(hs_out + (size_t)row * HH + c0) = o;
  }
}

// repack all 4 W [256,256] fp32 row-major into fragment-contiguous f16
__global__ void repack_w_kernel(const float* __restrict__ W2, const float* __restrict__ W3,
                                const float* __restrict__ W4, const float* __restrict__ W5,
                                __half* __restrict__ Wf) {
  int t = blockIdx.x * blockDim.x + threadIdx.x;  // 4*65536 threads
  int which = t >> 16;
  int u = t & 65535;
  const float* W = (which == 0) ? W2 : (which == 1) ? W3 : (which == 2) ? W4 : W5;
  int b = u & 7;
  int lane = (u >> 3) & 63;
  int tile = (u >> 9) & 15;
  int ks = u >> 13;
  int k = ks * 32 + (lane >> 4) * 8 + b;
  int c = tile * 16 + (lane & 15);
  Wf[t] = __float2half(W[k * HH + c]);
}

// MFMA transform: out = tanh(aggH @ W + b) [* norm_src -> f16 hs]  or fp32 h (last layer)
__global__ __launch_bounds__(256) void gemm_mfma_kernel(
    const __half* __restrict__ aggH, const __half* __restrict__ Wf,
    const float* __restrict__ bias, const float* __restrict__ norm_src,
    __half* __restrict__ hs_out, float* h_out) {
  int w = threadIdx.x >> 6;
  int lane = threadIdx.x & 63;
  int l15 = lane & 15, l4 = lane >> 4;
  int row0 = blockIdx.x * 64;
  floatx4 acc[4][4];
#pragma unroll
  for (int m = 0; m < 4; ++m)
#pragma unroll
    for (int n = 0; n < 4; ++n) acc[m][n] = (floatx4)(0.0f);

#pragma unroll
  for (int ks = 0; ks < 8; ++ks) {
    int k0 = ks * 32 + l4 * 8;
    half8 af[4];
#pragma unroll
    for (int m = 0; m < 4; ++m)
      af[m] = *(const half8*)(aggH + (size_t)(row0 + m * 16 + l15) * HH + k0);
    half8 bf[4];
#pragma unroll
    for (int n = 0; n < 4; ++n)
      bf[n] = *(const half8*)(Wf + ((size_t)(ks * 16 + w * 4 + n) * 64 + lane) * 8);
#pragma unroll
    for (int m = 0; m < 4; ++m)
#pragma unroll
      for (int n = 0; n < 4; ++n)
        acc[m][n] = __builtin_amdgcn_mfma_f32_16x16x32_f16(af[m], bf[n], acc[m][n], 0, 0, 0);
  }

  float ns[16];
  if (!h_out) {
#pragma unroll
    for (int m = 0; m < 4; ++m)
#pragma unroll
      for (int r = 0; r < 4; ++r) ns[m * 4 + r] = norm_src[row0 + m * 16 + l4 * 4 + r];
  }
#pragma unroll
  for (int n = 0; n < 4; ++n) {
    int c = w * 64 + n * 16 + l15;
    float bb = bias[c];
#pragma unroll
    for (int m = 0; m < 4; ++m) {
#pragma unroll
      for (int r = 0; r < 4; ++r) {
        int row = row0 + m * 16 + l4 * 4 + r;
        float y = fast_tanh(acc[m][n][r] + bb);
        if (h_out) {
          h_out[(size_t)row * HH + c] = y;
        } else {
          hs_out[(size_t)row * HH + c] = (__half)(y * ns[m * 4 + r]);
        }
      }
    }
  }
}

__global__ void mean_kernel(const float* __restrict__ h, const int* __restrict__ g_ptr,
                            float* __restrict__ emb) {
  int g = blockIdx.x;
  int j = threadIdx.x;  // 256 threads
  int s = g_ptr[g], e = g_ptr[g + 1];
  float sum = 0.f;
  for (int n = s; n < e; ++n) sum += h[(size_t)n * HH + j];
  int cnt = e - s;
  emb[(size_t)g * HH + j] = (cnt > 0) ? sum / (float)cnt : 0.0f;
}

__global__ __launch_bounds__(128) void mlp_kernel(const float* __restrict__ emb,
                                                  const float* __restrict__ Wl1,
                                                  const float* __restrict__ bl1,
                                                  const float* __restrict__ Wl2,
                                                  const float* __restrict__ bl2,
                                                  float* __restrict__ pred) {
  __shared__ float se[256];
  __shared__ float sh[128];
  int g = blockIdx.x, t = threadIdx.x;
  se[t] = emb[(size_t)g * HH + t];
  se[t + 128] = emb[(size_t)g * HH + t + 128];
  __syncthreads();
  float acc = bl1[t];
  for (int k = 0; k < 256; ++k) acc += se[k] * Wl1[k * 128 + t];
  float he = (acc > 0.f) ? acc : 0.01f * acc;
  sh[t] = he * Wl2[t];
  __syncthreads();
  if (t < 64) sh[t] += sh[t + 64];
  __syncthreads();
  if (t < 64) {
    float v = sh[t];
    for (int off = 32; off > 0; off >>= 1) v += __shfl_down(v, off);
    if (t == 0) {
      float z = v + bl2[0];
      pred[g] = 1.0f / (1.0f + expf(-z));
    }
  }
}

extern "C" void kernel_launch(void* const* d_in, const int* in_sizes, int n_in,
                              void* d_out, int out_size, void* d_ws, size_t ws_size,
                              hipStream_t stream) {
  const int* src = (const int*)d_in[0];
  const int* dst = (const int*)d_in[1];
  const int* gid = (const int*)d_in[2];
  const float* W1 = (const float*)d_in[3];
  const float* b1 = (const float*)d_in[4];
  const float* W2 = (const float*)d_in[5];
  const float* b2 = (const float*)d_in[6];
  const float* W3 = (const float*)d_in[7];
  const float* b3 = (const float*)d_in[8];
  const float* W4 = (const float*)d_in[9];
  const float* b4 = (const float*)d_in[10];
  const float* W5 = (const float*)d_in[11];
  const float* b5 = (const float*)d_in[12];
  const float* Wl1 = (const float*)d_in[13];
  const float* bl1 = (const float*)d_in[14];
  const float* Wl2 = (const float*)d_in[15];
  const float* bl2 = (const float*)d_in[16];

  char* ws = (char*)d_ws;
  size_t off = 0;
  auto alloc = [&](size_t bytes) -> void* {
    void* p = ws + off;
    off += (bytes + 255) & ~(size_t)255;
    return p;
  };

  int* col = (int*)alloc((size_t)EE * 4);
  int* row_ptr = (int*)alloc((size_t)(NN + 1) * 4);
  int* hist_d = (int*)alloc((size_t)NB * NC * 4);
  int* hist_s = (int*)alloc((size_t)NB * NC * 4);
  int* bsum = (int*)alloc(1024 * 4);
  int* boffs = (int*)alloc(1025 * 4);
  int* g_ptr = (int*)alloc((size_t)(GG + 1) * 4);
  int* deg_out = (int*)alloc((size_t)NN * 4);
  float* norm_src = (float*)alloc((size_t)NN * 4);
  float* norm_dst = (float*)alloc((size_t)NN * 4);
  float4* xs1 = (float4*)alloc((size_t)NN * 16);
  float4* agg4 = (float4*)alloc((size_t)NN * 16);
  __half* Wf = (__half*)alloc((size_t)4 * HH * HH * 2);
  // union area (102.4 MB): keys (25.6) -> src_sorted (25.6) -> aggH (disjoint lifetimes)
  void* unionp = alloc((size_t)NN * HH * 2);
  unsigned* keys = (unsigned*)unionp;
  int* src_sorted = (int*)unionp;
  __half* aggH = (__half*)unionp;

  float* outp = (float*)d_out;
  float* pred = outp;
  float* emb = outp + GG;
  float* hreg = outp + GG + (size_t)GG * HH;  // final h fp32 (fully written at layer 5)
  __half* hs = (__half*)hreg;                 // f16 hs in d_out h region (round-6 scheme)

  gptr_kernel<<<(NN + 255) / 256, 256, 0, stream>>>(gid, g_ptr);
  repack_w_kernel<<<1024, 256, 0, stream>>>(W2, W3, W4, W5, Wf);

  const int nscan = NB * NC;                  // 611,524
  const int nbA = (nscan + 1023) / 1024;      // 598
  hist_dual_kernel<<<NC, 256, 0, stream>>>(dst, src, hist_d, hist_s);
  // dst chain -> col, row_ptr
  scanA4_kernel<<<nbA, 256, 0, stream>>>(hist_d, nscan, bsum);
  scanB_kernel<<<1, 1024, 0, stream>>>(bsum, nbA, boffs);
  addC4_kernel<<<(nscan + 255) / 256, 256, 0, stream>>>(hist_d, nscan, boffs);
  scatter1_kernel<<<NC, 256, 0, stream>>>(src, dst, hist_d, keys);
  bucket_kernel<<<NB, 256, 0, stream>>>(keys, hist_d, col, row_ptr);
  // src chain -> deg_out
  scanA4_kernel<<<nbA, 256, 0, stream>>>(hist_s, nscan, bsum);
  scanB_kernel<<<1, 1024, 0, stream>>>(bsum, nbA, boffs);
  addC4_kernel<<<(nscan + 255) / 256, 256, 0, stream>>>(hist_s, nscan, boffs);
  scatter_src_kernel<<<NC, 256, 0, stream>>>(src, hist_s, src_sorted);
  buckethist_kernel<<<NB, 256, 0, stream>>>(src_sorted, hist_s, deg_out);

  feature_kernel<<<(NN + 255) / 256, 256, 0, stream>>>(row_ptr, deg_out, norm_src, norm_dst, xs1);

  // layer 1 (K=4)
  spmm4_kernel<<<(NN + 255) / 256, 256, 0, stream>>>(row_ptr, col, xs1, norm_dst, agg4);
  transform4_kernel<<<NN / 64, 256, 0, stream>>>((const float*)agg4, W1, b1, norm_src, hs);

  // layers 2-5: split spmm -> aggH (ws union), gemm -> hs in place (f16) or fp32 h at layer 5
  const float* bs[4] = {b2, b3, b4, b5};
  for (int l = 0; l < 4; ++l) {
    spmm256_kernel<<<NN / 4, 256, 0, stream>>>(row_ptr, col, hs, norm_dst, aggH);
    gemm_mfma_kernel<<<NN / 64, 256, 0, stream>>>(
        aggH, Wf + (size_t)l * HH * HH, bs[l], norm_src,
        hs, (l == 3) ? hreg : (float*)nullptr);
  }

  mean_kernel<<<GG, 256, 0, stream>>>(hreg, g_ptr, emb);
  mlp_kernel<<<GG, 128, 0, stream>>>(emb, Wl1, bl1, Wl2, bl2, pred);
}

// Round 10
// 2747.984 us; speedup vs baseline: 1.0966x; 1.0303x over previous
//
#include <hip/hip_runtime.h>
#include <hip/hip_fp16.h>

#define NN 200000
#define EE 6400000
#define GG 1024
#define HH 256
#define NB 782        // buckets = ceil(NN/256)
#define NC 782        // edge chunks = ceil(EE/8192)
#define CHUNK 8192
#define CAP 9216      // LDS stage capacity per bucket
#define LP 264        // LDS A-tile pitch in halves (256 + 8 pad)

typedef _Float16 half8 __attribute__((ext_vector_type(8)));
typedef float floatx4 __attribute__((ext_vector_type(4)));
typedef unsigned int uintx2 __attribute__((ext_vector_type(2)));

__device__ __forceinline__ float fast_tanh(float x) {
  float e = __expf(2.0f * x);
  return 1.0f - 2.0f / (e + 1.0f);
}

// g_ptr from sorted gid boundaries
__global__ void gptr_kernel(const int* __restrict__ gid, int* __restrict__ g_ptr) {
  int n = blockIdx.x * blockDim.x + threadIdx.x;
  if (n >= NN) return;
  int g = gid[n];
  int gp = (n == 0) ? -1 : gid[n - 1];
  for (int x = gp + 1; x <= g; ++x) g_ptr[x] = n;
  if (n == NN - 1) {
    for (int x = g + 1; x <= GG; ++x) g_ptr[x] = NN;
  }
}

// per-chunk bucket counts of dst AND src in one pass, bucket-major outputs
__global__ __launch_bounds__(256) void hist_dual_kernel(const int* __restrict__ dst,
                                                        const int* __restrict__ src,
                                                        int* __restrict__ hist_d,
                                                        int* __restrict__ hist_s) {
  __shared__ int hd[NB];
  __shared__ int hsb[NB];
  int c = blockIdx.x, t = threadIdx.x;
  for (int b = t; b < NB; b += 256) { hd[b] = 0; hsb[b] = 0; }
  __syncthreads();
  int e0 = c * CHUNK, e1 = min(e0 + CHUNK, EE);
  for (int e = e0 + t; e < e1; e += 256) {
    atomicAdd(&hd[dst[e] >> 8], 1);
    atomicAdd(&hsb[src[e] >> 8], 1);
  }
  __syncthreads();
  for (int b = t; b < NB; b += 256) {
    hist_d[b * NC + c] = hd[b];
    hist_s[b * NC + c] = hsb[b];
  }
}

// scan stage A: 1024 elems/block (4/thread), in-place exclusive, emits block sums
__global__ __launch_bounds__(256) void scanA4_kernel(int* __restrict__ a, int n,
                                                     int* __restrict__ bsum) {
  __shared__ int ws4[4];
  int t = threadIdx.x;
  int base = blockIdx.x * 1024 + t * 4;
  int v0 = 0, v1 = 0, v2 = 0, v3 = 0;
  if (base + 3 < n) {
    int4 q = *(const int4*)(a + base);
    v0 = q.x; v1 = q.y; v2 = q.z; v3 = q.w;
  } else {
    if (base + 0 < n) v0 = a[base + 0];
    if (base + 1 < n) v1 = a[base + 1];
    if (base + 2 < n) v2 = a[base + 2];
    if (base + 3 < n) v3 = a[base + 3];
  }
  int s = v0 + v1 + v2 + v3;
  int lane = t & 63, w = t >> 6;
  int x = s;
  for (int off = 1; off < 64; off <<= 1) {
    int y = __shfl_up(x, off);
    if (lane >= off) x += y;
  }
  if (lane == 63) ws4[w] = x;
  __syncthreads();
  if (t == 0) {
    int acc = 0;
    for (int k = 0; k < 4; ++k) { int tmp = ws4[k]; ws4[k] = acc; acc += tmp; }
  }
  __syncthreads();
  int e = ws4[w] + x - s;
  int o0 = e, o1 = e + v0, o2 = o1 + v1, o3 = o2 + v2;
  if (base + 3 < n) {
    int4 q; q.x = o0; q.y = o1; q.z = o2; q.w = o3;
    *(int4*)(a + base) = q;
  } else {
    if (base + 0 < n) a[base + 0] = o0;
    if (base + 1 < n) a[base + 1] = o1;
    if (base + 2 < n) a[base + 2] = o2;
    if (base + 3 < n) a[base + 3] = o3;
  }
  if (t == 255) bsum[blockIdx.x] = ws4[3] + x;
}

// stage B: single-block exclusive scan of block sums (nb <= 1024)
__global__ __launch_bounds__(1024) void scanB_kernel(const int* __restrict__ bsum, int nb,
                                                     int* __restrict__ boffs) {
  __shared__ int wsum[16];
  int t = threadIdx.x;
  int lane = t & 63, w = t >> 6;
  int v = (t < nb) ? bsum[t] : 0;
  int x = v;
  for (int off = 1; off < 64; off <<= 1) {
    int y = __shfl_up(x, off);
    if (lane >= off) x += y;
  }
  if (lane == 63) wsum[w] = x;
  __syncthreads();
  if (t < 16) {
    int s = wsum[t];
    for (int off = 1; off < 16; off <<= 1) {
      int y = __shfl_up(s, off);
      if (t >= off) s += y;
    }
    wsum[t] = s;
  }
  __syncthreads();
  int waveoff = (w > 0) ? wsum[w - 1] : 0;
  int excl = waveoff + (x - v);
  if (t <= nb) boffs[t] = excl;
}

__global__ void addC4_kernel(int* __restrict__ a, int n, const int* __restrict__ boffs) {
  int i = blockIdx.x * blockDim.x + threadIdx.x;
  if (i < n) a[i] += boffs[i >> 10];
}

// fused scatter: keys ((d&255)<<24|src) by dst-bucket AND src values by src-bucket
__global__ __launch_bounds__(256) void scatter_dual_kernel(const int* __restrict__ src,
                                                           const int* __restrict__ dst,
                                                           const int* __restrict__ hist_d,
                                                           const int* __restrict__ hist_s,
                                                           unsigned* __restrict__ keys,
                                                           int* __restrict__ src_sorted) {
  __shared__ int cur_d[NB];
  __shared__ int cur_s[NB];
  int c = blockIdx.x, t = threadIdx.x;
  for (int b = t; b < NB; b += 256) {
    cur_d[b] = hist_d[b * NC + c];
    cur_s[b] = hist_s[b * NC + c];
  }
  __syncthreads();
  int e0 = c * CHUNK, e1 = min(e0 + CHUNK, EE);
  for (int e = e0 + t; e < e1; e += 256) {
    int d = dst[e], s = src[e];
    int posd = atomicAdd(&cur_d[d >> 8], 1);
    keys[posd] = ((unsigned)(d & 255) << 24) | (unsigned)s;
    int poss = atomicAdd(&cur_s[s >> 8], 1);
    src_sorted[poss] = s;
  }
}

// pass-2: per-bucket counting sort in LDS; emits col (coalesced) + row_ptr
__global__ __launch_bounds__(256) void bucket_kernel(const unsigned* __restrict__ keys,
                                                     const int* __restrict__ hist_d,
                                                     int* __restrict__ col,
                                                     int* __restrict__ row_ptr) {
  __shared__ int rhist[256];
  __shared__ int rcur[256];
  __shared__ int ws4[4];
  __shared__ int stage[CAP];
  int b = blockIdx.x, t = threadIdx.x;
  int row0 = b << 8;
  int p0 = hist_d[b * NC];
  int p1 = (b == NB - 1) ? EE : hist_d[(b + 1) * NC];
  int cnt = p1 - p0;
  rhist[t] = 0;
  __syncthreads();
  for (int i = t; i < cnt; i += 256) {
    atomicAdd(&rhist[keys[p0 + i] >> 24], 1);
  }
  __syncthreads();
  int v = rhist[t];
  int lane = t & 63, w = t >> 6;
  int x = v;
  for (int off = 1; off < 64; off <<= 1) {
    int y = __shfl_up(x, off);
    if (lane >= off) x += y;
  }
  if (lane == 63) ws4[w] = x;
  __syncthreads();
  if (t == 0) {
    int acc = 0;
    for (int k = 0; k < 4; ++k) { int tmp = ws4[k]; ws4[k] = acc; acc += tmp; }
  }
  __syncthreads();
  int excl = ws4[w] + x - v;
  rcur[t] = excl;
  int row = row0 + t;
  if (row < NN) row_ptr[row] = p0 + excl;
  if (b == NB - 1 && t == 0) row_ptr[NN] = EE;
  __syncthreads();
  for (int i = t; i < cnt; i += 256) {
    unsigned k = keys[p0 + i];
    int pos = atomicAdd(&rcur[k >> 24], 1);
    int s = (int)(k & 0xFFFFFFu);
    if (pos < CAP) stage[pos] = s;
    else col[p0 + pos] = s;  // overflow guard (statistically never)
  }
  __syncthreads();
  int lim = min(cnt, CAP);
  for (int i = t; i < lim; i += 256) col[p0 + i] = stage[i];
}

// per-src-bucket 256-bin LDS histogram -> deg_out
__global__ __launch_bounds__(256) void buckethist_kernel(const int* __restrict__ sorted,
                                                         const int* __restrict__ hist_s,
                                                         int* __restrict__ deg_out) {
  __shared__ int h[256];
  int b = blockIdx.x, t = threadIdx.x;
  int p0 = hist_s[b * NC];
  int p1 = (b == NB - 1) ? EE : hist_s[(b + 1) * NC];
  h[t] = 0;
  __syncthreads();
  for (int i = p0 + t; i < p1; i += 256) atomicAdd(&h[sorted[i] & 255], 1);
  __syncthreads();
  int n = (b << 8) + t;
  if (n < NN) deg_out[n] = h[t];
}

__global__ void feature_kernel(const int* __restrict__ row_ptr, const int* __restrict__ deg_out,
                               float* __restrict__ norm_src, float* __restrict__ norm_dst,
                               float4* __restrict__ xs1) {
  int n = blockIdx.x * blockDim.x + threadIdx.x;
  if (n >= NN) return;
  int dii = row_ptr[n + 1] - row_ptr[n];
  int doo = deg_out[n];
  float di = (float)dii;
  float dofl = (float)doo;
  float ns = rsqrtf(fmaxf(dofl, 1.0f));
  float nd = rsqrtf(fmaxf(di, 1.0f));
  norm_src[n] = ns;
  norm_dst[n] = nd;
  float h1 = di;
  float h2 = (di - 3.0f > 0.0f) ? 1.0f : 0.0f;
  float h3 = 3.0f / di;
  float h4 = (di - 4.0f > 0.0f) ? 1.0f : 0.0f;
  float4 o;
  o.x = h1 * ns; o.y = h2 * ns; o.z = h3 * ns; o.w = h4 * ns;
  xs1[n] = o;
}

__global__ void spmm4_kernel(const int* __restrict__ rp, const int* __restrict__ col,
                             const float4* __restrict__ xs1, const float* __restrict__ norm_dst,
                             float4* __restrict__ agg4) {
  int n = blockIdx.x * blockDim.x + threadIdx.x;
  if (n >= NN) return;
  int e0 = rp[n], e1 = rp[n + 1];
  float ax = 0.f, ay = 0.f, az = 0.f, aw = 0.f;
  for (int e = e0; e < e1; ++e) {
    int s = __builtin_nontemporal_load(&col[e]);
    float4 v = xs1[s];
    ax += v.x; ay += v.y; az += v.z; aw += v.w;
  }
  float nd = norm_dst[n];
  float4 o; o.x = ax * nd; o.y = ay * nd; o.z = az * nd; o.w = aw * nd;
  agg4[n] = o;
}

__device__ __forceinline__ void acc_row(uint2 v, float& a0, float& a1, float& a2, float& a3) {
  __half2 h0 = *reinterpret_cast<__half2*>(&v.x);
  __half2 h1 = *reinterpret_cast<__half2*>(&v.y);
  float2 f0 = __half22float2(h0);
  float2 f1 = __half22float2(h1);
  a0 += f0.x; a1 += f0.y; a2 += f1.x; a3 += f1.y;
}

// one wave per dst row; lane holds 4 features; 16x unrolled; scalar gathers; f16 out
__global__ __launch_bounds__(256) void spmm256_kernel(
    const int* __restrict__ rp, const int* __restrict__ col,
    const __half* __restrict__ hs, const float* __restrict__ norm_dst,
    __half* __restrict__ aggH) {
  int wid = (blockIdx.x * blockDim.x + threadIdx.x) >> 6;
  int lane = threadIdx.x & 63;
  if (wid >= NN) return;
  int e0 = rp[wid], e1 = rp[wid + 1];
  float a0 = 0.f, a1 = 0.f, a2 = 0.f, a3 = 0.f;
  const __half* hp = hs + lane * 4;
  int e = e0;
  for (; e + 16 <= e1; e += 16) {
    int s[16];
#pragma unroll
    for (int u = 0; u < 16; ++u)
      s[u] = __builtin_amdgcn_readfirstlane(__builtin_nontemporal_load(&col[e + u]));
    uint2 v[16];
#pragma unroll
    for (int u = 0; u < 16; ++u) v[u] = *(const uint2*)(hp + (size_t)s[u] * HH);
#pragma unroll
    for (int u = 0; u < 16; ++u) acc_row(v[u], a0, a1, a2, a3);
  }
  for (; e + 4 <= e1; e += 4) {
    int s[4];
#pragma unroll
    for (int u = 0; u < 4; ++u)
      s[u] = __builtin_amdgcn_readfirstlane(__builtin_nontemporal_load(&col[e + u]));
    uint2 v[4];
#pragma unroll
    for (int u = 0; u < 4; ++u) v[u] = *(const uint2*)(hp + (size_t)s[u] * HH);
#pragma unroll
    for (int u = 0; u < 4; ++u) acc_row(v[u], a0, a1, a2, a3);
  }
  for (; e < e1; ++e) {
    int s = __builtin_amdgcn_readfirstlane(__builtin_nontemporal_load(&col[e]));
    uint2 v = *(const uint2*)(hp + (size_t)s * HH);
    acc_row(v, a0, a1, a2, a3);
  }
  float nd = norm_dst[wid];
  __half2 p0 = __floats2half2_rn(a0 * nd, a1 * nd);
  __half2 p1 = __floats2half2_rn(a2 * nd, a3 * nd);
  uintx2 o;
  o[0] = *(unsigned*)&p0;
  o[1] = *(unsigned*)&p1;
  __builtin_nontemporal_store(o, (uintx2*)(aggH + (size_t)wid * HH + lane * 4));
}

// layer-1 transform (K=4), VALU path
__global__ __launch_bounds__(256) void transform4_kernel(
    const float* __restrict__ agg, const float* __restrict__ W, const float* __restrict__ b,
    const float* __restrict__ norm_src, __half* __restrict__ hs_out) {
  __shared__ float tile[64 * 4];
  int t = threadIdx.x;
  int rowbase = blockIdx.x * 64;
  const float4* srcp = (const float4*)(agg + (size_t)rowbase * 4);
  float4* dst4 = (float4*)tile;
  for (int i = t; i < 64; i += 256) dst4[i] = srcp[i];
  __syncthreads();
  int w = t >> 6, lane = t & 63;
  int c0 = lane * 4;
  float acc[16][4];
#pragma unroll
  for (int r = 0; r < 16; ++r) {
    acc[r][0] = 0.f; acc[r][1] = 0.f; acc[r][2] = 0.f; acc[r][3] = 0.f;
  }
  const float* tw = tile + (size_t)(w * 16) * 4;
#pragma unroll
  for (int k = 0; k < 4; ++k) {
    float4 wv = *(const float4*)(W + (size_t)k * HH + c0);
#pragma unroll
    for (int r = 0; r < 16; ++r) {
      float a = tw[r * 4 + k];
      acc[r][0] += a * wv.x;
      acc[r][1] += a * wv.y;
      acc[r][2] += a * wv.z;
      acc[r][3] += a * wv.w;
    }
  }
  float4 bv = *(const float4*)(b + c0);
#pragma unroll
  for (int r = 0; r < 16; ++r) {
    int row = rowbase + w * 16 + r;
    float ns = norm_src[row];
    float y0 = fast_tanh(acc[r][0] + bv.x) * ns;
    float y1 = fast_tanh(acc[r][1] + bv.y) * ns;
    float y2 = fast_tanh(acc[r][2] + bv.z) * ns;
    float y3 = fast_tanh(acc[r][3] + bv.w) * ns;
    __half2 p0 = __floats2half2_rn(y0, y1);
    __half2 p1 = __floats2half2_rn(y2, y3);
    uint2 o = make_uint2(*(unsigned*)&p0, *(unsigned*)&p1);
    *(uint2*)(hs_out + (size_t)row * HH + c0) = o;
  }
}

// repack all 4 W [256,256] fp32 row-major into fragment-contiguous f16
__global__ void repack_w_kernel(const float* __restrict__ W2, const float* __restrict__ W3,
                                const float* __restrict__ W4, const float* __restrict__ W5,
                                __half* __restrict__ Wf) {
  int t = blockIdx.x * blockDim.x + threadIdx.x;  // 4*65536 threads
  int which = t >> 16;
  int u = t & 65535;
  const float* W = (which == 0) ? W2 : (which == 1) ? W3 : (which == 2) ? W4 : W5;
  int b = u & 7;
  int lane = (u >> 3) & 63;
  int tile = (u >> 9) & 15;
  int ks = u >> 13;
  int k = ks * 32 + (lane >> 4) * 8 + b;
  int c = tile * 16 + (lane & 15);
  Wf[t] = __float2half(W[k * HH + c]);
}

// MFMA transform with LDS-staged A: out = tanh(A @ W + b) [* norm_src -> f16] or fp32 h
__global__ __launch_bounds__(256) void gemm_mfma_kernel(
    const __half* __restrict__ aggH, const __half* __restrict__ Wf,
    const float* __restrict__ bias, const float* __restrict__ norm_src,
    __half* __restrict__ hs_out, float* h_out) {
  __shared__ __half tileA[64 * LP];
  int t = threadIdx.x;
  int w = t >> 6;
  int lane = t & 63;
  int row0 = blockIdx.x * 64;

  // stage A tile (32 KB) once: coalesced 16B loads, linear LDS writes
  {
    const uint4* g = (const uint4*)(aggH + (size_t)row0 * HH);
    for (int i = t; i < 64 * (HH / 8); i += 256) {
      int r = i >> 5;       // 32 uint4 per row
      int c = i & 31;
      *(uint4*)(tileA + r * LP + c * 8) = g[i];
    }
  }
  __syncthreads();

  int l15 = lane & 15, l4 = lane >> 4;
  floatx4 acc[4][4];
#pragma unroll
  for (int m = 0; m < 4; ++m)
#pragma unroll
    for (int n = 0; n < 4; ++n) acc[m][n] = (floatx4)(0.0f);

#pragma unroll
  for (int ks = 0; ks < 8; ++ks) {
    int k0 = ks * 32 + l4 * 8;
    half8 af[4];
#pragma unroll
    for (int m = 0; m < 4; ++m)
      af[m] = *(const half8*)(tileA + (m * 16 + l15) * LP + k0);
    half8 bf[4];
#pragma unroll
    for (int n = 0; n < 4; ++n)
      bf[n] = *(const half8*)(Wf + ((size_t)(ks * 16 + w * 4 + n) * 64 + lane) * 8);
#pragma unroll
    for (int m = 0; m < 4; ++m)
#pragma unroll
      for (int n = 0; n < 4; ++n)
        acc[m][n] = __builtin_amdgcn_mfma_f32_16x16x32_f16(af[m], bf[n], acc[m][n], 0, 0, 0);
  }

  float ns[16];
  if (!h_out) {
#pragma unroll
    for (int m = 0; m < 4; ++m)
#pragma unroll
      for (int r = 0; r < 4; ++r) ns[m * 4 + r] = norm_src[row0 + m * 16 + l4 * 4 + r];
  }
#pragma unroll
  for (int n = 0; n < 4; ++n) {
    int c = w * 64 + n * 16 + l15;
    float bb = bias[c];
#pragma unroll
    for (int m = 0; m < 4; ++m) {
#pragma unroll
      for (int r = 0; r < 4; ++r) {
        int row = row0 + m * 16 + l4 * 4 + r;
        float y = fast_tanh(acc[m][n][r] + bb);
        if (h_out) {
          h_out[(size_t)row * HH + c] = y;
        } else {
          hs_out[(size_t)row * HH + c] = (__half)(y * ns[m * 4 + r]);
        }
      }
    }
  }
}

__global__ void mean_kernel(const float* __restrict__ h, const int* __restrict__ g_ptr,
                            float* __restrict__ emb) {
  int g = blockIdx.x;
  int j = threadIdx.x;  // 256 threads
  int s = g_ptr[g], e = g_ptr[g + 1];
  float sum = 0.f;
  for (int n = s; n < e; ++n) sum += h[(size_t)n * HH + j];
  int cnt = e - s;
  emb[(size_t)g * HH + j] = (cnt > 0) ? sum / (float)cnt : 0.0f;
}

__global__ __launch_bounds__(128) void mlp_kernel(const float* __restrict__ emb,
                                                  const float* __restrict__ Wl1,
                                                  const float* __restrict__ bl1,
                                                  const float* __restrict__ Wl2,
                                                  const float* __restrict__ bl2,
                                                  float* __restrict__ pred) {
  __shared__ float se[256];
  __shared__ float sh[128];
  int g = blockIdx.x, t = threadIdx.x;
  se[t] = emb[(size_t)g * HH + t];
  se[t + 128] = emb[(size_t)g * HH + t + 128];
  __syncthreads();
  float acc = bl1[t];
  for (int k = 0; k < 256; ++k) acc += se[k] * Wl1[k * 128 + t];
  float he = (acc > 0.f) ? acc : 0.01f * acc;
  sh[t] = he * Wl2[t];
  __syncthreads();
  if (t < 64) sh[t] += sh[t + 64];
  __syncthreads();
  if (t < 64) {
    float v = sh[t];
    for (int off = 32; off > 0; off >>= 1) v += __shfl_down(v, off);
    if (t == 0) {
      float z = v + bl2[0];
      pred[g] = 1.0f / (1.0f + expf(-z));
    }
  }
}

extern "C" void kernel_launch(void* const* d_in, const int* in_sizes, int n_in,
                              void* d_out, int out_size, void* d_ws, size_t ws_size,
                              hipStream_t stream) {
  const int* src = (const int*)d_in[0];
  const int* dst = (const int*)d_in[1];
  const int* gid = (const int*)d_in[2];
  const float* W1 = (const float*)d_in[3];
  const float* b1 = (const float*)d_in[4];
  const float* W2 = (const float*)d_in[5];
  const float* b2 = (const float*)d_in[6];
  const float* W3 = (const float*)d_in[7];
  const float* b3 = (const float*)d_in[8];
  const float* W4 = (const float*)d_in[9];
  const float* b4 = (const float*)d_in[10];
  const float* W5 = (const float*)d_in[11];
  const float* b5 = (const float*)d_in[12];
  const float* Wl1 = (const float*)d_in[13];
  const float* bl1 = (const float*)d_in[14];
  const float* Wl2 = (const float*)d_in[15];
  const float* bl2 = (const float*)d_in[16];

  char* ws = (char*)d_ws;
  size_t off = 0;
  auto alloc = [&](size_t bytes) -> void* {
    void* p = ws + off;
    off += (bytes + 255) & ~(size_t)255;
    return p;
  };

  int* col = (int*)alloc((size_t)EE * 4);
  int* row_ptr = (int*)alloc((size_t)(NN + 1) * 4);
  int* hist_d = (int*)alloc((size_t)NB * NC * 4);
  int* hist_s = (int*)alloc((size_t)NB * NC * 4);
  int* bsum = (int*)alloc(1024 * 4);
  int* boffs = (int*)alloc(1025 * 4);
  int* g_ptr = (int*)alloc((size_t)(GG + 1) * 4);
  int* deg_out = (int*)alloc((size_t)NN * 4);
  float* norm_src = (float*)alloc((size_t)NN * 4);
  float* norm_dst = (float*)alloc((size_t)NN * 4);
  float4* xs1 = (float4*)alloc((size_t)NN * 16);
  float4* agg4 = (float4*)alloc((size_t)NN * 16);
  __half* Wf = (__half*)alloc((size_t)4 * HH * HH * 2);
  // union area (102.4 MB): [keys 25.6 | src_sorted 25.6] -> aggH (disjoint lifetimes)
  char* unionp = (char*)alloc((size_t)NN * HH * 2);
  unsigned* keys = (unsigned*)unionp;
  int* src_sorted = (int*)(unionp + ((size_t)EE * 4 + 255 & ~(size_t)255));
  __half* aggH = (__half*)unionp;

  float* outp = (float*)d_out;
  float* pred = outp;
  float* emb = outp + GG;
  float* hreg = outp + GG + (size_t)GG * HH;  // final h fp32 (fully written at layer 5)
  __half* hs = (__half*)hreg;                 // f16 hs in d_out h region

  gptr_kernel<<<(NN + 255) / 256, 256, 0, stream>>>(gid, g_ptr);
  repack_w_kernel<<<1024, 256, 0, stream>>>(W2, W3, W4, W5, Wf);

  const int nscan = NB * NC;                  // 611,524
  const int nbA = (nscan + 1023) / 1024;      // 598
  hist_dual_kernel<<<NC, 256, 0, stream>>>(dst, src, hist_d, hist_s);
  scanA4_kernel<<<nbA, 256, 0, stream>>>(hist_d, nscan, bsum);
  scanB_kernel<<<1, 1024, 0, stream>>>(bsum, nbA, boffs);
  addC4_kernel<<<(nscan + 255) / 256, 256, 0, stream>>>(hist_d, nscan, boffs);
  scanA4_kernel<<<nbA, 256, 0, stream>>>(hist_s, nscan, bsum);
  scanB_kernel<<<1, 1024, 0, stream>>>(bsum, nbA, boffs);
  addC4_kernel<<<(nscan + 255) / 256, 256, 0, stream>>>(hist_s, nscan, boffs);
  scatter_dual_kernel<<<NC, 256, 0, stream>>>(src, dst, hist_d, hist_s, keys, src_sorted);
  bucket_kernel<<<NB, 256, 0, stream>>>(keys, hist_d, col, row_ptr);
  buckethist_kernel<<<NB, 256, 0, stream>>>(src_sorted, hist_s, deg_out);

  feature_kernel<<<(NN + 255) / 256, 256, 0, stream>>>(row_ptr, deg_out, norm_src, norm_dst, xs1);

  // layer 1 (K=4)
  spmm4_kernel<<<(NN + 255) / 256, 256, 0, stream>>>(row_ptr, col, xs1, norm_dst, agg4);
  transform4_kernel<<<NN / 64, 256, 0, stream>>>((const float*)agg4, W1, b1, norm_src, hs);

  // layers 2-5: split spmm -> aggH (ws union), gemm -> hs (f16) or fp32 h at layer 5
  const float* bs[4] = {b2, b3, b4, b5};
  for (int l = 0; l < 4; ++l) {
    spmm256_kernel<<<NN / 4, 256, 0, stream>>>(row_ptr, col, hs, norm_dst, aggH);
    gemm_mfma_kernel<<<NN / 64, 256, 0, stream>>>(
        aggH, Wf + (size_t)l * HH * HH, bs[l], norm_src,
        hs, (l == 3) ? hreg : (float*)nullptr);
  }

  mean_kernel<<<GG, 256, 0, stream>>>(hreg, g_ptr, emb);
  mlp_kernel<<<GG, 128, 0, stream>>>(emb, Wl1, bl1, Wl2, bl2, pred);
}